// Round 2
// baseline (358.536 us; speedup 1.0000x reference)
//
#include <hip/hip_runtime.h>

// CandidateScorer on MI355X (gfx950).
//
// Math (exact rewrite of the reference):
//   gp-part of combined is candidate-independent      -> folded into bias b1'
//   go/to gathers take only 361 distinct values each  -> precomputed tables
//   h1[n,j] = relu(T_go[go[n],j] + T_to[to[n],j] + (cand @ W1c)[n,j] + b1'[j])
//   scores  = relu(h1 @ W2 + b2) @ W3 + b3   (GEMM3 fused into GEMM2 epilogue)
//
// R1..R6: 128^2 2-phase gemm2 at ~1012 TF (frozen as gemm2_128 fallback).
// R12: 8-phase 256^2 port FAILED (absmax 4.2): staged tile t+2 into the live
//   buffer at PH1 while tile t's ds_reads (spread over PH0-PH2) still read it.
// R13 (this round): race-free 8-phase schedule. Reads regrouped so each LDS
//   region is fully consumed before the phase that overwrites it:
//     PH0 reads all B (8 frags) + A[mh0] (8); PH1 reads A[mh1] (8).
//     => B halves free after PH0's 2nd barrier, A halves after PH1's.
//   Stage order per tile: PH0:(t+1,A-hi)->other buf; PH1:(t+2,B-lo);
//   PH2:(t+2,B-hi); PH3:(t+2,A-lo). vmcnt(6) at tile end leaves exactly
//   tile t+2's 3 staged halves in flight; tile t+1 is proven landed.
//   bias/w3 loads moved after the K-loop to keep the vmcnt ledger exact.

using bf16x8 = __attribute__((ext_vector_type(8))) __bf16;
using f32x4  = __attribute__((ext_vector_type(4))) float;
using i32x4  = __attribute__((ext_vector_type(4))) int;

__device__ __forceinline__ unsigned short f2bf(float f) {
  unsigned int u = __float_as_uint(f);
  u += 0x7fffu + ((u >> 16) & 1u);          // round-to-nearest-even
  return (unsigned short)(u >> 16);
}
__device__ __forceinline__ float bf2f(unsigned int s) {
  return __uint_as_float(s << 16);
}

// Async global->LDS, 16B per lane. LDS dest is wave-uniform base + lane*16.
__device__ __forceinline__ void async_copy16(const void* g, void* l) {
  __builtin_amdgcn_global_load_lds(
      (__attribute__((address_space(1))) void*)(unsigned long long)g,
      (__attribute__((address_space(3))) void*)(unsigned int)(unsigned long long)l,
      16, 0, 0);
}

// ---------------------------------------------------------------- pool
// 64 blocks x 256 threads: wave w reduces channel bx*4+w (fully parallel).
// Blocks 0-3 additionally init b1p = b1 (atomic target for prep's b1p range).
__global__ void pool_kernel(const float* __restrict__ pfm, float* __restrict__ gp,
                            const float* __restrict__ b1, float* __restrict__ b1p) {
  int t = threadIdx.x, bx = blockIdx.x;
  int wave = t >> 6, lane = t & 63;
  int c = bx * 4 + wave;
  float s = 0.f;
  for (int i = lane; i < 361; i += 64) s += pfm[c * 361 + i];
#pragma unroll
  for (int off = 32; off > 0; off >>= 1) s += __shfl_down(s, off, 64);
  if (lane == 0) gp[c] = s * (1.0f / 361.0f);
  if (bx < 4) b1p[bx * 256 + t] = b1[bx * 256 + t];
}

// ---------------------------------------------------------------- fused prep
// Block ranges (long pole first):
//   [0,368)      Ttab (bf16): T[s][pos][j] = sum_c pfm[c][pos]*W1[s*256+c][j]
//   [368,496)    b1p[j] += sum over 8 channels of gp[c]*W1[512+c][j] (atomic)
//   [496,752)    w2T[n][k] = bf16(W2[k][n])  (64x64 LDS-tiled transpose)
//   [752,1008)   go/to decode
//   [1008,1264)  scores = b3
//   [1264,1520)  w1cT[n][k] = bf16(W1[768+k][n])
__global__ void prep_kernel(const float* __restrict__ pfm, const float* __restrict__ cand,
                            const float* __restrict__ W1, const float* __restrict__ gp,
                            const float* __restrict__ W2, const float* __restrict__ b3,
                            int* __restrict__ go_off, int* __restrict__ to_off,
                            float* __restrict__ scores,
                            unsigned short* __restrict__ w1cT,
                            unsigned short* __restrict__ w2T,
                            unsigned short* __restrict__ Tb,
                            float* __restrict__ b1p) {
  __shared__ __align__(16) char smem[16640];
  int bx = blockIdx.x, t = threadIdx.x;

  if (bx < 368) {
    int b = bx;                      // 2 * 46 * 4 = 368 blocks
    int s = b / 184;
    int rem = b % 184;
    int p8 = rem >> 2;
    int jc = rem & 3;
    int j = jc * 256 + t;
    float (*pf)[256] = (float(*)[256])smem;   // [8][256] = 8KB
#pragma unroll
    for (int i = 0; i < 8; i++) {
      int p = p8 * 8 + i;
      pf[i][t] = (p < 361) ? pfm[t * 361 + p] : 0.f;   // t = channel
    }
    __syncthreads();
    float acc[8] = {0.f, 0.f, 0.f, 0.f, 0.f, 0.f, 0.f, 0.f};
    for (int c = 0; c < 256; c++) {
      float w = W1[(size_t)(s * 256 + c) * 1024 + j];
#pragma unroll
      for (int i = 0; i < 8; i++) acc[i] += pf[i][c] * w;
    }
#pragma unroll
    for (int i = 0; i < 8; i++) {
      int p = p8 * 8 + i;
      if (p < 361) Tb[((size_t)s * 361 + p) * 1024 + j] = f2bf(acc[i]);
    }
  } else if (bx < 496) {
    int b = bx - 368;                // 128 blocks: (jc 0..3) x (cchunk 0..31)
    int j = (b & 3) * 256 + t;
    int c0 = (b >> 2) * 8;
    float acc = 0.f;
#pragma unroll
    for (int i = 0; i < 8; i++)
      acc += gp[c0 + i] * W1[(size_t)(512 + c0 + i) * 1024 + j];
    atomicAdd(&b1p[j], acc);
  } else if (bx < 752) {
    int b = bx - 496;                // 256 tiles (16 x 16)
    float (*Ts)[65] = (float(*)[65])smem;     // [64][65] = 16640 B
    int kt = b >> 4, nt = b & 15;
#pragma unroll
    for (int i = 0; i < 4; i++) {
      int c = i * 256 + t;           // 1024 f32x4 chunks
      int r = c >> 4, ch = c & 15;
      f32x4 v = *(const f32x4*)&W2[(size_t)(kt * 64 + r) * 1024 + nt * 64 + ch * 4];
      Ts[r][ch * 4 + 0] = v[0]; Ts[r][ch * 4 + 1] = v[1];
      Ts[r][ch * 4 + 2] = v[2]; Ts[r][ch * 4 + 3] = v[3];
    }
    __syncthreads();
#pragma unroll
    for (int i = 0; i < 2; i++) {
      int c = i * 256 + t;           // 512 out-chunks of 8 bf16
      int n = c >> 3, ch = c & 7;
      unsigned short pack[8];
#pragma unroll
      for (int j = 0; j < 8; j++) pack[j] = f2bf(Ts[ch * 8 + j][n]);
      *(i32x4*)&w2T[(size_t)(nt * 64 + n) * 1024 + kt * 64 + ch * 8] = *(i32x4*)pack;
    }
  } else if (bx < 1008) {
    int n = (bx - 752) * 256 + t;
    const float* cf = cand + (size_t)n * 64;
    int gr = min(max((int)(cf[5] * 18.0f), 0), 18);
    int gc = min(max((int)(cf[6] * 18.0f), 0), 18);
    int tr = min(max((int)(cf[7] * 18.0f), 0), 18);
    int tc = min(max((int)(cf[8] * 18.0f), 0), 18);
    go_off[n] = gr * 19 + gc;
    to_off[n] = tr * 19 + tc;
  } else if (bx < 1264) {
    scores[(bx - 1008) * 256 + t] = b3[0];
  } else {
    int o = (bx - 1264) * 256 + t;   // < 65536
    int n = o >> 6, k = o & 63;
    w1cT[o] = f2bf(W1[(size_t)(768 + k) * 1024 + n]);
  }
}

// ---------------------------------------------------------------- GEMM1 (fused)

// h1(65536 x 1024) = relu(cand(f32) @ W1c + T_go[go] + T_to[to] + b1p)
// 128x128 tile, K=64 single step. A staged via f32 load + convert + ds_write;
// B via async_copy16. LDS XOR-swizzled (chunk (row,s) holds kchunk s^(row&7)).
__launch_bounds__(256, 2)
__global__ void gemm1_kernel(const float* __restrict__ cand,
                             const unsigned short* __restrict__ w1cT,
                             unsigned short* __restrict__ h1out,
                             const unsigned short* __restrict__ Tb,
                             const int* __restrict__ go_off,
                             const int* __restrict__ to_off,
                             const float* __restrict__ bias) {
  __shared__ __align__(16) char smem[34816];           // max(32K stage, 34K Cs)
  unsigned short* As = (unsigned short*)smem;          // [128][64] 16KB
  unsigned short* Bs = (unsigned short*)(smem + 16384);// [128][64] 16KB
  unsigned short* Cs = (unsigned short*)smem;          // [128][136] bf16 (aliased)

  const int tid  = threadIdx.x;
  const int lane = tid & 63;
  const int wave = tid >> 6;
  const int wm   = wave & 1;
  const int wn   = wave >> 1;
  const int quad = lane >> 4;
  const int r16  = lane & 15;

  const int bx    = blockIdx.x;
  const int xcd   = bx & 7;
  const int seq   = bx >> 3;
  const int ntile = seq & 7;
  const int mtile = ((seq >> 3) << 3) | xcd;
  const long rowbase = (long)mtile * 128;
  const int  colbase = ntile * 128;

  // ---- stage A: load f32, convert, ds_write (4 chunks of 16B per thread)
#pragma unroll
  for (int i = 0; i < 4; i++) {
    int c = i * 256 + tid;                 // physical chunk
    int row = c >> 3, s = c & 7;
    int kc = s ^ (row & 7);                // logical k-chunk
    const float* src = cand + (rowbase + row) * 64 + kc * 8;
    f32x4 v0 = *(const f32x4*)src;
    f32x4 v1 = *(const f32x4*)(src + 4);
    unsigned int p[4];
    p[0] = f2bf(v0[0]) | ((unsigned int)f2bf(v0[1]) << 16);
    p[1] = f2bf(v0[2]) | ((unsigned int)f2bf(v0[3]) << 16);
    p[2] = f2bf(v1[0]) | ((unsigned int)f2bf(v1[1]) << 16);
    p[3] = f2bf(v1[2]) | ((unsigned int)f2bf(v1[3]) << 16);
    *(i32x4*)&As[c * 8] = *(i32x4*)p;
  }
  // ---- stage B: async copy w1cT tile (4 chunks per thread)
#pragma unroll
  for (int i = 0; i < 4; i++) {
    int c = i * 256 + tid;
    int row = c >> 3, s = c & 7;
    int kc = s ^ (row & 7);
    async_copy16(w1cT + (colbase + row) * 64 + kc * 8, &Bs[c * 8]);
  }
  __syncthreads();

  const f32x4 zero4 = {0.f, 0.f, 0.f, 0.f};
  f32x4 acc[4][4];
#pragma unroll
  for (int i = 0; i < 4; i++)
#pragma unroll
    for (int j = 0; j < 4; j++) acc[i][j] = zero4;

#pragma unroll
  for (int ks = 0; ks < 2; ks++) {
    bf16x8 af[4], bfv[4];
#pragma unroll
    for (int mi = 0; mi < 4; mi++) {
      int r = wm * 64 + mi * 16 + r16;
      int phys = (ks * 4 + quad) ^ (r16 & 7);
      af[mi] = *(const bf16x8*)&As[r * 64 + phys * 8];
    }
#pragma unroll
    for (int ni = 0; ni < 4; ni++) {
      int r = wn * 64 + ni * 16 + r16;
      int phys = (ks * 4 + quad) ^ (r16 & 7);
      bfv[ni] = *(const bf16x8*)&Bs[r * 64 + phys * 8];
    }
#pragma unroll
    for (int mi = 0; mi < 4; mi++)
#pragma unroll
      for (int ni = 0; ni < 4; ni++)
        acc[mi][ni] = __builtin_amdgcn_mfma_f32_16x16x32_bf16(af[mi], bfv[ni],
                                                              acc[mi][ni], 0, 0, 0);
  }
  __syncthreads();   // staging LDS dead; Cs takes over

  // Phase 1: Cs[r][c] = bf16(T_go[go[r]][c] + T_to[to[r]][c] + bias[c]).
#pragma unroll
  for (int i = 0; i < 8; i++) {
    int c = i * 256 + tid;                    // 2048 chunks of 8 cols
    int r = c >> 4, ch = c & 15;
    long grow = rowbase + r;
    const unsigned short* tg = Tb + (long)go_off[grow] * 1024 + colbase + ch * 8;
    const unsigned short* tt = Tb + 361L * 1024 + (long)to_off[grow] * 1024 + colbase + ch * 8;
    i32x4 ga = *(const i32x4*)tg;
    i32x4 gb = *(const i32x4*)tt;
    const float* bp = bias + colbase + ch * 8;
    f32x4 b0 = *(const f32x4*)bp;
    f32x4 b1v = *(const f32x4*)(bp + 4);
    unsigned int p[4];
#pragma unroll
    for (int w = 0; w < 4; w++) {
      unsigned int ua = (unsigned int)ga[w], ub = (unsigned int)gb[w];
      float lo = bf2f(ua & 0xffffu) + bf2f(ub & 0xffffu);
      float hi = bf2f(ua >> 16)     + bf2f(ub >> 16);
      lo += (w < 2) ? b0[w * 2]     : b1v[(w - 2) * 2];
      hi += (w < 2) ? b0[w * 2 + 1] : b1v[(w - 2) * 2 + 1];
      p[w] = f2bf(lo) | ((unsigned int)f2bf(hi) << 16);
    }
    *(i32x4*)&Cs[r * 136 + ch * 8] = *(i32x4*)p;
  }
  __syncthreads();
  // Phase 2: in-place RMW — each (rloc,cloc) touched by exactly one thread.
  // C/D layout: col = lane&15, row = quad*4 + reg  (m89/m91-verified)
#pragma unroll
  for (int mi = 0; mi < 4; mi++) {
#pragma unroll
    for (int reg = 0; reg < 4; reg++) {
      int rloc = wm * 64 + mi * 16 + quad * 4 + reg;
#pragma unroll
      for (int ni = 0; ni < 4; ni++) {
        int cloc = wn * 64 + ni * 16 + r16;
        float v = acc[mi][ni][reg] + bf2f(Cs[rloc * 136 + cloc]);
        Cs[rloc * 136 + cloc] = f2bf(fmaxf(v, 0.f));
      }
    }
  }
  __syncthreads();
  // Phase 3: 16B-coalesced global stores.
#pragma unroll
  for (int i = 0; i < 8; i++) {
    int c = i * 256 + tid;
    int r = c >> 4, cc = c & 15;
    *(i32x4*)(h1out + (rowbase + r) * 1024 + colbase + cc * 8) =
        *(const i32x4*)&Cs[r * 136 + cc * 8];
  }
}

// ---------------------------------------------------------------- GEMM2 (8-phase 256^2)

// LDS map (byte offsets into 128 KiB dynamic smem), per buffer b = t&1:
//   A(b) = b*65536          : 2 halves x [128 rows][8 slots of 16B]   (32 KB)
//   B(b) = b*65536 + 32768  : same                                    (32 KB)
// Stage-slot ss = 4t + j stages half O[j] of tile t, O = {B-lo,B-hi,A-lo,A-hi}
// i.e. p = (ss&3)^2 with p: 0=A-lo 1=A-hi 2=B-lo 3=B-hi. 2 loads/thread/slot.
// Chunk c = row*8 + s holds logical k-chunk s^(row&7) (XOR swizzle via
// pre-swizzled global source; read side applies the same involution).
__device__ __forceinline__ void stage_half(const unsigned short* __restrict__ A,
                                           const unsigned short* __restrict__ BT,
                                           char* smem, long rowbase, long colbase,
                                           int ss, int tid) {
  const int t = ss >> 2;
  const int p = (ss & 3) ^ 2;
  const unsigned short* src = (p < 2) ? A : BT;
  const long rbase = ((p < 2) ? rowbase : colbase) + (long)((p & 1) * 128);
  char* dst = smem + (t & 1) * 65536 + (p >> 1) * 32768 + (p & 1) * 16384;
  const long k0 = (long)t * 64;
#pragma unroll
  for (int j = 0; j < 2; j++) {
    const int c = j * 512 + tid;
    const int lrow = c >> 3;
    const int kc = (c & 7) ^ (lrow & 7);
    async_copy16(src + (rbase + lrow) * 1024 + k0 + kc * 8, dst + c * 16);
  }
}

// Fragment read: tile-row r in [0,256), logical k-chunk kq in [0,8).
__device__ __forceinline__ bf16x8 lds_frag(const char* base, int r, int kq) {
  const int lrow = r & 127;
  return *(const bf16x8*)(base + (r >> 7) * 16384 + lrow * 128 +
                          ((kq ^ (lrow & 7)) * 16));
}

// One K-tile (BK=64), 4 phases. Region-free protocol:
//   PH0 reads A[mh0](8) + ALL B(8)  -> both B halves free after PH0 bar#2
//   PH1 reads A[mh1](8)             -> both A halves free after PH1 bar#2
//   (per-wave lgkmcnt(0) after bar#1 drains its reads; bar#2 publishes)
// Stage slots: PH0: ss0   = (t+1, A-hi) -> other buffer (always safe)
//              PH1: ss0+1 = (t+2, B-lo) -> this buffer, freed in PH0
//              PH2: ss0+2 = (t+2, B-hi) -> freed in PH0
//              PH3: ss0+3 = (t+2, A-lo) -> freed in PH1
// MFMA quadrants: PH0 (mh0,n01), PH1 (mh0,n23), PH2 (mh1,n01), PH3 (mh1,n23).
// VMODE: 6 = vmcnt(6) before final barrier (3 newest slots = t+2's stay in
// flight; everything of tile t+1 proven landed), 0 = full drain, -1 = none.
template <int NSTAGE, int VMODE>
__device__ __forceinline__ void ktile(char* smem,
                                      const unsigned short* __restrict__ A,
                                      const unsigned short* __restrict__ BT,
                                      long rowbase, long colbase, int tid,
                                      int wm128, int wn64, int quad, int r16,
                                      int t, int ss0, f32x4 (&acc)[8][4]) {
  const char* a_base = smem + (t & 1) * 65536;
  const char* b_base = a_base + 32768;
  bf16x8 af0[4][2], af1[4][2], bf[4][2];

  // ---- PH0: read A[mh0] + all B; stage (t+1, A-hi); MFMA (mh0, n01)
#pragma unroll
  for (int mi = 0; mi < 4; mi++)
#pragma unroll
    for (int ks = 0; ks < 2; ks++)
      af0[mi][ks] = lds_frag(a_base, wm128 + mi * 16 + r16, ks * 4 + quad);
#pragma unroll
  for (int ni = 0; ni < 4; ni++)
#pragma unroll
    for (int ks = 0; ks < 2; ks++)
      bf[ni][ks] = lds_frag(b_base, wn64 + ni * 16 + r16, ks * 4 + quad);
  if (NSTAGE >= 1) stage_half(A, BT, smem, rowbase, colbase, ss0, tid);
  __builtin_amdgcn_s_barrier();
  asm volatile("s_waitcnt lgkmcnt(0)" ::: "memory");
  __builtin_amdgcn_s_setprio(1);
#pragma unroll
  for (int mi = 0; mi < 4; mi++)
#pragma unroll
    for (int ni = 0; ni < 2; ni++)
#pragma unroll
      for (int ks = 0; ks < 2; ks++)
        acc[mi][ni] = __builtin_amdgcn_mfma_f32_16x16x32_bf16(af0[mi][ks], bf[ni][ks],
                                                              acc[mi][ni], 0, 0, 0);
  __builtin_amdgcn_s_setprio(0);
  __builtin_amdgcn_s_barrier();

  // ---- PH1: read A[mh1]; stage (t+2, B-lo); MFMA (mh0, n23)
#pragma unroll
  for (int mi = 0; mi < 4; mi++)
#pragma unroll
    for (int ks = 0; ks < 2; ks++)
      af1[mi][ks] = lds_frag(a_base, wm128 + 64 + mi * 16 + r16, ks * 4 + quad);
  if (NSTAGE >= 2) stage_half(A, BT, smem, rowbase, colbase, ss0 + 1, tid);
  __builtin_amdgcn_s_barrier();
  asm volatile("s_waitcnt lgkmcnt(0)" ::: "memory");
  __builtin_amdgcn_s_setprio(1);
#pragma unroll
  for (int mi = 0; mi < 4; mi++)
#pragma unroll
    for (int ni = 2; ni < 4; ni++)
#pragma unroll
      for (int ks = 0; ks < 2; ks++)
        acc[mi][ni] = __builtin_amdgcn_mfma_f32_16x16x32_bf16(af0[mi][ks], bf[ni][ks],
                                                              acc[mi][ni], 0, 0, 0);
  __builtin_amdgcn_s_setprio(0);
  __builtin_amdgcn_s_barrier();

  // ---- PH2: stage (t+2, B-hi); MFMA (mh1, n01)
  if (NSTAGE >= 3) stage_half(A, BT, smem, rowbase, colbase, ss0 + 2, tid);
  __builtin_amdgcn_s_barrier();
  __builtin_amdgcn_s_setprio(1);
#pragma unroll
  for (int mi = 0; mi < 4; mi++)
#pragma unroll
    for (int ni = 0; ni < 2; ni++)
#pragma unroll
      for (int ks = 0; ks < 2; ks++)
        acc[4 + mi][ni] = __builtin_amdgcn_mfma_f32_16x16x32_bf16(af1[mi][ks], bf[ni][ks],
                                                                  acc[4 + mi][ni], 0, 0, 0);
  __builtin_amdgcn_s_setprio(0);
  __builtin_amdgcn_s_barrier();

  // ---- PH3: stage (t+2, A-lo); MFMA (mh1, n23); counted vmcnt; barrier
  if (NSTAGE >= 4) stage_half(A, BT, smem, rowbase, colbase, ss0 + 3, tid);
  __builtin_amdgcn_s_barrier();
  __builtin_amdgcn_s_setprio(1);
#pragma unroll
  for (int mi = 0; mi < 4; mi++)
#pragma unroll
    for (int ni = 2; ni < 4; ni++)
#pragma unroll
      for (int ks = 0; ks < 2; ks++)
        acc[4 + mi][ni] = __builtin_amdgcn_mfma_f32_16x16x32_bf16(af1[mi][ks], bf[ni][ks],
                                                                  acc[4 + mi][ni], 0, 0, 0);
  __builtin_amdgcn_s_setprio(0);
  if (VMODE == 6)      asm volatile("s_waitcnt vmcnt(6)" ::: "memory");
  else if (VMODE == 0) asm volatile("s_waitcnt vmcnt(0)" ::: "memory");
  __builtin_amdgcn_s_barrier();
}

// scores += relu(h1(65536x1024,bf16) @ W2 + b2) @ W3.
// 256x256 tile, BK=64, 8 waves (2Mx4N), per-wave output 128x64.
// Prologue stages ss 0..6 (tile0 + 3/4 of tile1), vmcnt(6); main loop stages
// 1 half-tile/phase, 3 half-tiles always in flight; epilogue drains once.
__launch_bounds__(512, 2)
__global__ void gemm2_kernel(const unsigned short* __restrict__ A,
                             const unsigned short* __restrict__ BT,
                             const float* __restrict__ bias,
                             const float* __restrict__ w3,
                             float* __restrict__ scores) {
  extern __shared__ __align__(16) char smem[];

  const int tid  = threadIdx.x;
  const int lane = tid & 63;
  const int wave = tid >> 6;
  const int wm128 = (wave & 1) * 128;
  const int wn64  = (wave >> 1) * 64;
  const int quad = lane >> 4;
  const int r16  = lane & 15;

  const int bx    = blockIdx.x;          // 1024 blocks = 256 mtiles x 4 ntiles
  const int xcd   = bx & 7;
  const int seq   = bx >> 3;
  const int ntile = seq & 3;
  const int mtile = ((seq >> 2) << 3) | xcd;
  const long rowbase = (long)mtile * 256;
  const long colbase = (long)ntile * 256;

  f32x4 acc[8][4];
#pragma unroll
  for (int i = 0; i < 8; i++)
#pragma unroll
    for (int j = 0; j < 4; j++) acc[i][j] = (f32x4){0.f, 0.f, 0.f, 0.f};

  // prologue: stage ss 0..6 (14 loads), wait until tile0 (ss0-3) landed.
  // (no other VMEM loads are outstanding: bias/w3 are loaded after the loop)
#pragma unroll
  for (int ss = 0; ss < 7; ss++)
    stage_half(A, BT, smem, rowbase, colbase, ss, tid);
  asm volatile("s_waitcnt vmcnt(6)" ::: "memory");
  __builtin_amdgcn_s_barrier();

  // main loop: tiles 0..13, staging ss 4t+7 .. 4t+10 during tile t,
  // vmcnt(6) once per tile (only tile t+2's 3 staged slots stay in flight).
#pragma unroll 1
  for (int i = 0; i < 7; i++) {
    ktile<4, 6>(smem, A, BT, rowbase, colbase, tid, wm128, wn64, quad, r16,
                2 * i,     8 * i + 7,  acc);
    ktile<4, 6>(smem, A, BT, rowbase, colbase, tid, wm128, wn64, quad, r16,
                2 * i + 1, 8 * i + 11, acc);
  }
  // epilogue tiles: stage last slot (ss63 = tile15 A-hi), drain, compute.
  ktile<1, 0>(smem, A, BT, rowbase, colbase, tid, wm128, wn64, quad, r16, 14, 63, acc);
  ktile<0, -1>(smem, A, BT, rowbase, colbase, tid, wm128, wn64, quad, r16, 15, 0, acc);

  // epilogue constants (loaded here so the main-loop vmcnt ledger is exact;
  // cannot be hoisted above the asm memory clobbers in the loop)
  float bias_r[4], w3_r[4];
#pragma unroll
  for (int ni = 0; ni < 4; ni++) {
    int col = (int)colbase + wn64 + ni * 16 + r16;
    bias_r[ni] = bias[col];
    w3_r[ni]   = w3[col];
  }

  // fused epilogue: relu(x + b2) dot w3, shfl-reduce over 16 cols, one
  // atomic per (row, wn) -> 4 atomics per row across the N=1024 extent.
#pragma unroll
  for (int mi = 0; mi < 8; mi++) {
#pragma unroll
    for (int reg = 0; reg < 4; reg++) {
      long row = rowbase + wm128 + mi * 16 + quad * 4 + reg;
      float part = 0.f;
#pragma unroll
      for (int ni = 0; ni < 4; ni++) {
        float v = fmaxf(acc[mi][ni][reg] + bias_r[ni], 0.f);
        part += v * w3_r[ni];
      }
      part += __shfl_xor(part, 1, 16);
      part += __shfl_xor(part, 2, 16);
      part += __shfl_xor(part, 4, 16);
      part += __shfl_xor(part, 8, 16);
      if (r16 == 0) atomicAdd(&scores[row], part);
    }
  }
}

// ---------------------------------------------------------------- GEMM2 fallback (R6)

// Frozen R6 winner (~1012 TF): used only if 128 KiB dynamic LDS is refused.
__launch_bounds__(256, 2)
__global__ void gemm2_128(const unsigned short* __restrict__ A,
                          const unsigned short* __restrict__ BT,
                          const float* __restrict__ bias,
                          const float* __restrict__ w3,
                          float* __restrict__ scores) {
  __shared__ unsigned short As[128 * 64];  // [row][k] 16KB
  __shared__ unsigned short Bs[128 * 64];  // [n][k]   16KB

  const int tid  = threadIdx.x;
  const int lane = tid & 63;
  const int wave = tid >> 6;
  const int wm   = wave & 1;
  const int wn   = wave >> 1;
  const int quad = lane >> 4;
  const int r16  = lane & 15;

  const int bx    = blockIdx.x;
  const int xcd   = bx & 7;
  const int seq   = bx >> 3;
  const int ntile = seq & 7;
  const int mtile = ((seq >> 3) << 3) | xcd;
  const long rowbase = (long)mtile * 128;
  const int  colbase = ntile * 128;

  const f32x4 zero4 = {0.f, 0.f, 0.f, 0.f};
  f32x4 acc[4][4];
#pragma unroll
  for (int i = 0; i < 4; i++)
#pragma unroll
    for (int j = 0; j < 4; j++) acc[i][j] = zero4;

  float bias_r[4], w3_r[4];
#pragma unroll
  for (int ni = 0; ni < 4; ni++) {
    int col = colbase + wn * 64 + ni * 16 + r16;
    bias_r[ni] = bias[col];
    w3_r[ni]   = w3[col];
  }

  int srow[4], skc[4];
#pragma unroll
  for (int i = 0; i < 4; i++) {
    int c = i * 256 + tid;
    srow[i] = c >> 3;
    skc[i]  = (c & 7) ^ (srow[i] & 7);
  }

  for (int k0 = 0; k0 < 1024; k0 += 64) {
#pragma unroll
    for (int i = 0; i < 4; i++) {
      int c = i * 256 + tid;
      async_copy16(A + (rowbase + srow[i]) * 1024 + k0 + skc[i] * 8, &As[c * 8]);
    }
#pragma unroll
    for (int i = 0; i < 4; i++) {
      int c = i * 256 + tid;
      async_copy16(BT + (long)(colbase + srow[i]) * 1024 + k0 + skc[i] * 8, &Bs[c * 8]);
    }
    __syncthreads();

#pragma unroll
    for (int ks = 0; ks < 2; ks++) {
      bf16x8 af[4], bfv[4];
#pragma unroll
      for (int mi = 0; mi < 4; mi++) {
        int r = wm * 64 + mi * 16 + r16;
        int phys = (ks * 4 + quad) ^ (r16 & 7);
        af[mi] = *(const bf16x8*)&As[r * 64 + phys * 8];
      }
#pragma unroll
      for (int ni = 0; ni < 4; ni++) {
        int r = wn * 64 + ni * 16 + r16;
        int phys = (ks * 4 + quad) ^ (r16 & 7);
        bfv[ni] = *(const bf16x8*)&Bs[r * 64 + phys * 8];
      }
#pragma unroll
      for (int mi = 0; mi < 4; mi++)
#pragma unroll
        for (int ni = 0; ni < 4; ni++)
          acc[mi][ni] = __builtin_amdgcn_mfma_f32_16x16x32_bf16(af[mi], bfv[ni],
                                                                acc[mi][ni], 0, 0, 0);
    }
    __syncthreads();
  }

#pragma unroll
  for (int mi = 0; mi < 4; mi++) {
#pragma unroll
    for (int reg = 0; reg < 4; reg++) {
      long row = rowbase + wm * 64 + mi * 16 + quad * 4 + reg;
      float part = 0.f;
#pragma unroll
      for (int ni = 0; ni < 4; ni++) {
        float v = fmaxf(acc[mi][ni][reg] + bias_r[ni], 0.f);
        part += v * w3_r[ni];
      }
      part += __shfl_xor(part, 1, 16);
      part += __shfl_xor(part, 2, 16);
      part += __shfl_xor(part, 4, 16);
      part += __shfl_xor(part, 8, 16);
      if (r16 == 0) atomicAdd(&scores[row], part);
    }
  }
}

// ---------------------------------------------------------------- launch

extern "C" void kernel_launch(void* const* d_in, const int* in_sizes, int n_in,
                              void* d_out, int out_size, void* d_ws, size_t ws_size,
                              hipStream_t stream) {
  const float* pfm  = (const float*)d_in[0];  // (256,19,19)
  const float* cand = (const float*)d_in[1];  // (65536,64)
  const float* W1   = (const float*)d_in[2];  // (832,1024)
  const float* b1   = (const float*)d_in[3];  // (1024,)
  const float* W2   = (const float*)d_in[4];  // (1024,1024)
  const float* b2   = (const float*)d_in[5];  // (1024,)
  const float* W3   = (const float*)d_in[6];  // (1024,1)
  const float* b3   = (const float*)d_in[7];  // (1,)
  float* scores = (float*)d_out;              // (65536,)

  char* ws = (char*)d_ws;
  float*          gp      = (float*)(ws + 0);                // 1 KB
  float*          b1p     = (float*)(ws + 1024);             // 4 KB
  unsigned short* Tb      = (unsigned short*)(ws + 8192);    // 1,478,656
  int*            go_off  = (int*)(ws + 1486848);            // 256 KB
  int*            to_off  = (int*)(ws + 1748992);            // 256 KB
  unsigned short* w1cT    = (unsigned short*)(ws + 2011136); // 128 KB
  unsigned short* w2T     = (unsigned short*)(ws + 2142208); // 2 MB
  unsigned short* h1      = (unsigned short*)(ws + 4239360); // 128 MB
  // total ws need: 138,457,088 bytes
  if (ws_size < 138457088) return;  // loud correctness failure instead of corruption

  // one-time: opt in to 128 KiB dynamic LDS for the 8-phase gemm2.
  static int use256 = -1;
  if (use256 < 0) {
    use256 = (hipFuncSetAttribute((const void*)gemm2_kernel,
                                  hipFuncAttributeMaxDynamicSharedMemorySize,
                                  131072) == hipSuccess) ? 1 : 0;
  }

  pool_kernel<<<64, 256, 0, stream>>>(pfm, gp, b1, b1p);
  prep_kernel<<<1520, 256, 0, stream>>>(pfm, cand, W1, gp, W2, b3,
                                        go_off, to_off, scores, w1cT, w2T, Tb, b1p);
  // h1 = relu(cand@W1c + T_go[g] + T_to[t] + b1')   M=65536,K=64
  gemm1_kernel<<<4096, 256, 0, stream>>>(cand, w1cT, h1, Tb, go_off, to_off, b1p);
  // scores += relu(h1@W2 + b2) @ w3                 M=65536,K=1024
  if (use256) {
    gemm2_kernel<<<1024, 512, 131072, stream>>>(h1, w2T, b2, W3, scores);
  } else {
    gemm2_128<<<4096, 256, 0, stream>>>(h1, w2T, b2, W3, scores);
  }
}

// Round 3
// 286.647 us; speedup vs baseline: 1.2508x; 1.2508x over previous
//
#include <hip/hip_runtime.h>

// CandidateScorer on MI355X (gfx950).
//
// Math (exact rewrite of the reference):
//   gp-part of combined is candidate-independent      -> folded into bias b1'
//   go/to gathers take only 361 distinct values each  -> precomputed tables
//   h1[n,j] = relu(T_go[go[n],j] + T_to[to[n],j] + (cand @ W1c)[n,j] + b1'[j])
//   scores  = relu(h1 @ W2 + b2) @ W3 + b3   (GEMM3 fused into GEMM2 epilogue)
//
// R1..R6: 128^2 2-phase gemm2 at ~1012 TF (frozen as gemm2_128 fallback).
// R12: 8-phase 256^2 FAILED (WAR race). R13: race-free but SPILLED:
//   2 waves/SIMD = 256 unified regs; acc=128 AGPR + 96 live frag VGPRs
//   -> scratch (WRITE_SIZE 16->76 MB), MfmaUtil 24.7%, 227 us.
// R14 (this round): register-lean quadrant order (mh0,n01)(mh1,n01)
//   (mh1,n23)(mh0,n23): bf01 dies as bf23 is born -> peak frags 80.
//   Read-completion: A free after PH1, B-lo after PH2, B-hi after PH3.
//   Stage: PH0:(t+1,B-hi)->other buf; PH2:(t+2,A-lo); PH3:(t+2,A-hi)+
//   (t+2,B-lo). vmcnt(6)/tile keeps exactly t+2's 3 staged halves in
//   flight. PH3 has no ds_reads -> no lgkmcnt there.

using bf16x8 = __attribute__((ext_vector_type(8))) __bf16;
using f32x4  = __attribute__((ext_vector_type(4))) float;
using i32x4  = __attribute__((ext_vector_type(4))) int;

__device__ __forceinline__ unsigned short f2bf(float f) {
  unsigned int u = __float_as_uint(f);
  u += 0x7fffu + ((u >> 16) & 1u);          // round-to-nearest-even
  return (unsigned short)(u >> 16);
}
__device__ __forceinline__ float bf2f(unsigned int s) {
  return __uint_as_float(s << 16);
}

// Async global->LDS, 16B per lane. LDS dest is wave-uniform base + lane*16.
__device__ __forceinline__ void async_copy16(const void* g, void* l) {
  __builtin_amdgcn_global_load_lds(
      (__attribute__((address_space(1))) void*)(unsigned long long)g,
      (__attribute__((address_space(3))) void*)(unsigned int)(unsigned long long)l,
      16, 0, 0);
}

// ---------------------------------------------------------------- pool
// 64 blocks x 256 threads: wave w reduces channel bx*4+w (fully parallel).
// Blocks 0-3 additionally init b1p = b1 (atomic target for prep's b1p range).
__global__ void pool_kernel(const float* __restrict__ pfm, float* __restrict__ gp,
                            const float* __restrict__ b1, float* __restrict__ b1p) {
  int t = threadIdx.x, bx = blockIdx.x;
  int wave = t >> 6, lane = t & 63;
  int c = bx * 4 + wave;
  float s = 0.f;
  for (int i = lane; i < 361; i += 64) s += pfm[c * 361 + i];
#pragma unroll
  for (int off = 32; off > 0; off >>= 1) s += __shfl_down(s, off, 64);
  if (lane == 0) gp[c] = s * (1.0f / 361.0f);
  if (bx < 4) b1p[bx * 256 + t] = b1[bx * 256 + t];
}

// ---------------------------------------------------------------- fused prep
// Block ranges (long pole first):
//   [0,368)      Ttab (bf16): T[s][pos][j] = sum_c pfm[c][pos]*W1[s*256+c][j]
//   [368,496)    b1p[j] += sum over 8 channels of gp[c]*W1[512+c][j] (atomic)
//   [496,752)    w2T[n][k] = bf16(W2[k][n])  (64x64 LDS-tiled transpose)
//   [752,1008)   go/to decode
//   [1008,1264)  scores = b3
//   [1264,1520)  w1cT[n][k] = bf16(W1[768+k][n])
__global__ void prep_kernel(const float* __restrict__ pfm, const float* __restrict__ cand,
                            const float* __restrict__ W1, const float* __restrict__ gp,
                            const float* __restrict__ W2, const float* __restrict__ b3,
                            int* __restrict__ go_off, int* __restrict__ to_off,
                            float* __restrict__ scores,
                            unsigned short* __restrict__ w1cT,
                            unsigned short* __restrict__ w2T,
                            unsigned short* __restrict__ Tb,
                            float* __restrict__ b1p) {
  __shared__ __align__(16) char smem[16640];
  int bx = blockIdx.x, t = threadIdx.x;

  if (bx < 368) {
    int b = bx;                      // 2 * 46 * 4 = 368 blocks
    int s = b / 184;
    int rem = b % 184;
    int p8 = rem >> 2;
    int jc = rem & 3;
    int j = jc * 256 + t;
    float (*pf)[256] = (float(*)[256])smem;   // [8][256] = 8KB
#pragma unroll
    for (int i = 0; i < 8; i++) {
      int p = p8 * 8 + i;
      pf[i][t] = (p < 361) ? pfm[t * 361 + p] : 0.f;   // t = channel
    }
    __syncthreads();
    float acc[8] = {0.f, 0.f, 0.f, 0.f, 0.f, 0.f, 0.f, 0.f};
    for (int c = 0; c < 256; c++) {
      float w = W1[(size_t)(s * 256 + c) * 1024 + j];
#pragma unroll
      for (int i = 0; i < 8; i++) acc[i] += pf[i][c] * w;
    }
#pragma unroll
    for (int i = 0; i < 8; i++) {
      int p = p8 * 8 + i;
      if (p < 361) Tb[((size_t)s * 361 + p) * 1024 + j] = f2bf(acc[i]);
    }
  } else if (bx < 496) {
    int b = bx - 368;                // 128 blocks: (jc 0..3) x (cchunk 0..31)
    int j = (b & 3) * 256 + t;
    int c0 = (b >> 2) * 8;
    float acc = 0.f;
#pragma unroll
    for (int i = 0; i < 8; i++)
      acc += gp[c0 + i] * W1[(size_t)(512 + c0 + i) * 1024 + j];
    atomicAdd(&b1p[j], acc);
  } else if (bx < 752) {
    int b = bx - 496;                // 256 tiles (16 x 16)
    float (*Ts)[65] = (float(*)[65])smem;     // [64][65] = 16640 B
    int kt = b >> 4, nt = b & 15;
#pragma unroll
    for (int i = 0; i < 4; i++) {
      int c = i * 256 + t;           // 1024 f32x4 chunks
      int r = c >> 4, ch = c & 15;
      f32x4 v = *(const f32x4*)&W2[(size_t)(kt * 64 + r) * 1024 + nt * 64 + ch * 4];
      Ts[r][ch * 4 + 0] = v[0]; Ts[r][ch * 4 + 1] = v[1];
      Ts[r][ch * 4 + 2] = v[2]; Ts[r][ch * 4 + 3] = v[3];
    }
    __syncthreads();
#pragma unroll
    for (int i = 0; i < 2; i++) {
      int c = i * 256 + t;           // 512 out-chunks of 8 bf16
      int n = c >> 3, ch = c & 7;
      unsigned short pack[8];
#pragma unroll
      for (int j = 0; j < 8; j++) pack[j] = f2bf(Ts[ch * 8 + j][n]);
      *(i32x4*)&w2T[(size_t)(nt * 64 + n) * 1024 + kt * 64 + ch * 8] = *(i32x4*)pack;
    }
  } else if (bx < 1008) {
    int n = (bx - 752) * 256 + t;
    const float* cf = cand + (size_t)n * 64;
    int gr = min(max((int)(cf[5] * 18.0f), 0), 18);
    int gc = min(max((int)(cf[6] * 18.0f), 0), 18);
    int tr = min(max((int)(cf[7] * 18.0f), 0), 18);
    int tc = min(max((int)(cf[8] * 18.0f), 0), 18);
    go_off[n] = gr * 19 + gc;
    to_off[n] = tr * 19 + tc;
  } else if (bx < 1264) {
    scores[(bx - 1008) * 256 + t] = b3[0];
  } else {
    int o = (bx - 1264) * 256 + t;   // < 65536
    int n = o >> 6, k = o & 63;
    w1cT[o] = f2bf(W1[(size_t)(768 + k) * 1024 + n]);
  }
}

// ---------------------------------------------------------------- GEMM1 (fused)

// h1(65536 x 1024) = relu(cand(f32) @ W1c + T_go[go] + T_to[to] + b1p)
// 128x128 tile, K=64 single step. A staged via f32 load + convert + ds_write;
// B via async_copy16. LDS XOR-swizzled (chunk (row,s) holds kchunk s^(row&7)).
__launch_bounds__(256, 2)
__global__ void gemm1_kernel(const float* __restrict__ cand,
                             const unsigned short* __restrict__ w1cT,
                             unsigned short* __restrict__ h1out,
                             const unsigned short* __restrict__ Tb,
                             const int* __restrict__ go_off,
                             const int* __restrict__ to_off,
                             const float* __restrict__ bias) {
  __shared__ __align__(16) char smem[34816];           // max(32K stage, 34K Cs)
  unsigned short* As = (unsigned short*)smem;          // [128][64] 16KB
  unsigned short* Bs = (unsigned short*)(smem + 16384);// [128][64] 16KB
  unsigned short* Cs = (unsigned short*)smem;          // [128][136] bf16 (aliased)

  const int tid  = threadIdx.x;
  const int lane = tid & 63;
  const int wave = tid >> 6;
  const int wm   = wave & 1;
  const int wn   = wave >> 1;
  const int quad = lane >> 4;
  const int r16  = lane & 15;

  const int bx    = blockIdx.x;
  const int xcd   = bx & 7;
  const int seq   = bx >> 3;
  const int ntile = seq & 7;
  const int mtile = ((seq >> 3) << 3) | xcd;
  const long rowbase = (long)mtile * 128;
  const int  colbase = ntile * 128;

  // ---- stage A: load f32, convert, ds_write (4 chunks of 16B per thread)
#pragma unroll
  for (int i = 0; i < 4; i++) {
    int c = i * 256 + tid;                 // physical chunk
    int row = c >> 3, s = c & 7;
    int kc = s ^ (row & 7);                // logical k-chunk
    const float* src = cand + (rowbase + row) * 64 + kc * 8;
    f32x4 v0 = *(const f32x4*)src;
    f32x4 v1 = *(const f32x4*)(src + 4);
    unsigned int p[4];
    p[0] = f2bf(v0[0]) | ((unsigned int)f2bf(v0[1]) << 16);
    p[1] = f2bf(v0[2]) | ((unsigned int)f2bf(v0[3]) << 16);
    p[2] = f2bf(v1[0]) | ((unsigned int)f2bf(v1[1]) << 16);
    p[3] = f2bf(v1[2]) | ((unsigned int)f2bf(v1[3]) << 16);
    *(i32x4*)&As[c * 8] = *(i32x4*)p;
  }
  // ---- stage B: async copy w1cT tile (4 chunks per thread)
#pragma unroll
  for (int i = 0; i < 4; i++) {
    int c = i * 256 + tid;
    int row = c >> 3, s = c & 7;
    int kc = s ^ (row & 7);
    async_copy16(w1cT + (colbase + row) * 64 + kc * 8, &Bs[c * 8]);
  }
  __syncthreads();

  const f32x4 zero4 = {0.f, 0.f, 0.f, 0.f};
  f32x4 acc[4][4];
#pragma unroll
  for (int i = 0; i < 4; i++)
#pragma unroll
    for (int j = 0; j < 4; j++) acc[i][j] = zero4;

#pragma unroll
  for (int ks = 0; ks < 2; ks++) {
    bf16x8 af[4], bfv[4];
#pragma unroll
    for (int mi = 0; mi < 4; mi++) {
      int r = wm * 64 + mi * 16 + r16;
      int phys = (ks * 4 + quad) ^ (r16 & 7);
      af[mi] = *(const bf16x8*)&As[r * 64 + phys * 8];
    }
#pragma unroll
    for (int ni = 0; ni < 4; ni++) {
      int r = wn * 64 + ni * 16 + r16;
      int phys = (ks * 4 + quad) ^ (r16 & 7);
      bfv[ni] = *(const bf16x8*)&Bs[r * 64 + phys * 8];
    }
#pragma unroll
    for (int mi = 0; mi < 4; mi++)
#pragma unroll
      for (int ni = 0; ni < 4; ni++)
        acc[mi][ni] = __builtin_amdgcn_mfma_f32_16x16x32_bf16(af[mi], bfv[ni],
                                                              acc[mi][ni], 0, 0, 0);
  }
  __syncthreads();   // staging LDS dead; Cs takes over

  // Phase 1: Cs[r][c] = bf16(T_go[go[r]][c] + T_to[to[r]][c] + bias[c]).
#pragma unroll
  for (int i = 0; i < 8; i++) {
    int c = i * 256 + tid;                    // 2048 chunks of 8 cols
    int r = c >> 4, ch = c & 15;
    long grow = rowbase + r;
    const unsigned short* tg = Tb + (long)go_off[grow] * 1024 + colbase + ch * 8;
    const unsigned short* tt = Tb + 361L * 1024 + (long)to_off[grow] * 1024 + colbase + ch * 8;
    i32x4 ga = *(const i32x4*)tg;
    i32x4 gb = *(const i32x4*)tt;
    const float* bp = bias + colbase + ch * 8;
    f32x4 b0 = *(const f32x4*)bp;
    f32x4 b1v = *(const f32x4*)(bp + 4);
    unsigned int p[4];
#pragma unroll
    for (int w = 0; w < 4; w++) {
      unsigned int ua = (unsigned int)ga[w], ub = (unsigned int)gb[w];
      float lo = bf2f(ua & 0xffffu) + bf2f(ub & 0xffffu);
      float hi = bf2f(ua >> 16)     + bf2f(ub >> 16);
      lo += (w < 2) ? b0[w * 2]     : b1v[(w - 2) * 2];
      hi += (w < 2) ? b0[w * 2 + 1] : b1v[(w - 2) * 2 + 1];
      p[w] = f2bf(lo) | ((unsigned int)f2bf(hi) << 16);
    }
    *(i32x4*)&Cs[r * 136 + ch * 8] = *(i32x4*)p;
  }
  __syncthreads();
  // Phase 2: in-place RMW — each (rloc,cloc) touched by exactly one thread.
  // C/D layout: col = lane&15, row = quad*4 + reg  (m89/m91-verified)
#pragma unroll
  for (int mi = 0; mi < 4; mi++) {
#pragma unroll
    for (int reg = 0; reg < 4; reg++) {
      int rloc = wm * 64 + mi * 16 + quad * 4 + reg;
#pragma unroll
      for (int ni = 0; ni < 4; ni++) {
        int cloc = wn * 64 + ni * 16 + r16;
        float v = acc[mi][ni][reg] + bf2f(Cs[rloc * 136 + cloc]);
        Cs[rloc * 136 + cloc] = f2bf(fmaxf(v, 0.f));
      }
    }
  }
  __syncthreads();
  // Phase 3: 16B-coalesced global stores.
#pragma unroll
  for (int i = 0; i < 8; i++) {
    int c = i * 256 + tid;
    int r = c >> 4, cc = c & 15;
    *(i32x4*)(h1out + (rowbase + r) * 1024 + colbase + cc * 8) =
        *(const i32x4*)&Cs[r * 136 + cc * 8];
  }
}

// ---------------------------------------------------------------- GEMM2 (8-phase 256^2)

// LDS map (byte offsets into 128 KiB dynamic smem), per buffer b = t&1:
//   A(b) = b*65536          : 2 halves x [128 rows][8 slots of 16B]   (32 KB)
//   B(b) = b*65536 + 32768  : same                                    (32 KB)
// part p: 0=A-lo 1=A-hi 2=B-lo 3=B-hi. One call = 2 loads/thread = 16 KB.
// Chunk c = row*8 + s holds logical k-chunk s^(row&7) (XOR swizzle via
// pre-swizzled global source; read side applies the same involution).
__device__ __forceinline__ void stage_half(const unsigned short* __restrict__ A,
                                           const unsigned short* __restrict__ BT,
                                           char* smem, long rowbase, long colbase,
                                           int t, int p, int tid) {
  const unsigned short* src = (p < 2) ? A : BT;
  const long rbase = ((p < 2) ? rowbase : colbase) + (long)((p & 1) * 128);
  char* dst = smem + (t & 1) * 65536 + (p >> 1) * 32768 + (p & 1) * 16384;
  const long k0 = (long)t * 64;
#pragma unroll
  for (int j = 0; j < 2; j++) {
    const int c = j * 512 + tid;
    const int lrow = c >> 3;
    const int kc = (c & 7) ^ (lrow & 7);
    async_copy16(src + (rbase + lrow) * 1024 + k0 + kc * 8, dst + c * 16);
  }
}

// Fragment read: tile-row r in [0,256), logical k-chunk kq in [0,8).
__device__ __forceinline__ bf16x8 lds_frag(const char* base, int r, int kq) {
  const int lrow = r & 127;
  return *(const bf16x8*)(base + (r >> 7) * 16384 + lrow * 128 +
                          ((kq ^ (lrow & 7)) * 16));
}

// One K-tile (BK=64), 4 phases, register-lean quadrant order:
//   PH0: read A0(8)+B01(4); stage (t+1,B-hi)->other buf; MFMA (mh0,n01)
//   PH1: read A1(8);                                     MFMA (mh1,n01)
//   PH2: read B23(4);       stage (t+2,A-lo);            MFMA (mh1,n23)
//   PH3: no reads;          stage (t+2,A-hi)+(t+2,B-lo); MFMA (mh0,n23)
// Liveness peak = af0(32)+af1(32)+bf(16) = 80 VGPR; bf01/bf23 share regs.
// Read-completion (publishes via per-wave lgkmcnt before bar#2):
//   A-lo/A-hi fully read after PH1; B-lo after PH2; B-hi after PH3
//   -> every stage above targets a region already free. (t+2,B-hi) is
//   staged at tile t+1's PH0 (into t+1's other buffer = t+2's buffer,
//   whose previous tenant t was fully read by end of tile t).
// Ledger: 8 issues/tile (PH0:2, PH2:2, PH3:4). VMODE 6 = vmcnt(6) at tile
// end keeps exactly t+2's A-lo/A-hi/B-lo in flight, proving t+1 landed.
// NSTAGE: 2 = full, 1 = PH0 only, 0 = none.
template <int NSTAGE, int VMODE>
__device__ __forceinline__ void ktile(char* smem,
                                      const unsigned short* __restrict__ A,
                                      const unsigned short* __restrict__ BT,
                                      long rowbase, long colbase, int tid,
                                      int wm128, int wn64, int quad, int r16,
                                      int t, f32x4 (&acc)[8][4]) {
  const char* a_base = smem + (t & 1) * 65536;
  const char* b_base = a_base + 32768;
  bf16x8 af0[4][2], af1[4][2], bf01[2][2], bf23[2][2];

  // ---- PH0: read A0 + B01; stage (t+1, B-hi); MFMA (mh0, n01)
#pragma unroll
  for (int mi = 0; mi < 4; mi++)
#pragma unroll
    for (int ks = 0; ks < 2; ks++)
      af0[mi][ks] = lds_frag(a_base, wm128 + mi * 16 + r16, ks * 4 + quad);
#pragma unroll
  for (int ni = 0; ni < 2; ni++)
#pragma unroll
    for (int ks = 0; ks < 2; ks++)
      bf01[ni][ks] = lds_frag(b_base, wn64 + ni * 16 + r16, ks * 4 + quad);
  if (NSTAGE >= 1) stage_half(A, BT, smem, rowbase, colbase, t + 1, 3, tid);
  __builtin_amdgcn_s_barrier();
  asm volatile("s_waitcnt lgkmcnt(0)" ::: "memory");
  __builtin_amdgcn_s_setprio(1);
#pragma unroll
  for (int mi = 0; mi < 4; mi++)
#pragma unroll
    for (int ni = 0; ni < 2; ni++)
#pragma unroll
      for (int ks = 0; ks < 2; ks++)
        acc[mi][ni] = __builtin_amdgcn_mfma_f32_16x16x32_bf16(af0[mi][ks], bf01[ni][ks],
                                                              acc[mi][ni], 0, 0, 0);
  __builtin_amdgcn_s_setprio(0);
  __builtin_amdgcn_s_barrier();

  // ---- PH1: read A1; MFMA (mh1, n01)
#pragma unroll
  for (int mi = 0; mi < 4; mi++)
#pragma unroll
    for (int ks = 0; ks < 2; ks++)
      af1[mi][ks] = lds_frag(a_base, wm128 + 64 + mi * 16 + r16, ks * 4 + quad);
  __builtin_amdgcn_s_barrier();
  asm volatile("s_waitcnt lgkmcnt(0)" ::: "memory");
  __builtin_amdgcn_s_setprio(1);
#pragma unroll
  for (int mi = 0; mi < 4; mi++)
#pragma unroll
    for (int ni = 0; ni < 2; ni++)
#pragma unroll
      for (int ks = 0; ks < 2; ks++)
        acc[4 + mi][ni] = __builtin_amdgcn_mfma_f32_16x16x32_bf16(af1[mi][ks], bf01[ni][ks],
                                                                  acc[4 + mi][ni], 0, 0, 0);
  __builtin_amdgcn_s_setprio(0);
  __builtin_amdgcn_s_barrier();

  // ---- PH2: read B23; stage (t+2, A-lo); MFMA (mh1, n23)
#pragma unroll
  for (int ni = 0; ni < 2; ni++)
#pragma unroll
    for (int ks = 0; ks < 2; ks++)
      bf23[ni][ks] = lds_frag(b_base, wn64 + (2 + ni) * 16 + r16, ks * 4 + quad);
  if (NSTAGE >= 2) stage_half(A, BT, smem, rowbase, colbase, t + 2, 0, tid);
  __builtin_amdgcn_s_barrier();
  asm volatile("s_waitcnt lgkmcnt(0)" ::: "memory");
  __builtin_amdgcn_s_setprio(1);
#pragma unroll
  for (int mi = 0; mi < 4; mi++)
#pragma unroll
    for (int ni = 0; ni < 2; ni++)
#pragma unroll
      for (int ks = 0; ks < 2; ks++)
        acc[4 + mi][2 + ni] = __builtin_amdgcn_mfma_f32_16x16x32_bf16(af1[mi][ks], bf23[ni][ks],
                                                                      acc[4 + mi][2 + ni], 0, 0, 0);
  __builtin_amdgcn_s_setprio(0);
  __builtin_amdgcn_s_barrier();

  // ---- PH3: stage (t+2, A-hi) + (t+2, B-lo); MFMA (mh0, n23); vmcnt; bar
  if (NSTAGE >= 2) {
    stage_half(A, BT, smem, rowbase, colbase, t + 2, 1, tid);
    stage_half(A, BT, smem, rowbase, colbase, t + 2, 2, tid);
  }
  __builtin_amdgcn_s_barrier();
  __builtin_amdgcn_s_setprio(1);
#pragma unroll
  for (int mi = 0; mi < 4; mi++)
#pragma unroll
    for (int ni = 0; ni < 2; ni++)
#pragma unroll
      for (int ks = 0; ks < 2; ks++)
        acc[mi][2 + ni] = __builtin_amdgcn_mfma_f32_16x16x32_bf16(af0[mi][ks], bf23[ni][ks],
                                                                  acc[mi][2 + ni], 0, 0, 0);
  __builtin_amdgcn_s_setprio(0);
  if (VMODE == 6)      asm volatile("s_waitcnt vmcnt(6)" ::: "memory");
  else if (VMODE == 0) asm volatile("s_waitcnt vmcnt(0)" ::: "memory");
  __builtin_amdgcn_s_barrier();
}

// scores += relu(h1(65536x1024,bf16) @ W2 + b2) @ W3.
// 256x256 tile, BK=64, 8 waves (2Mx4N), per-wave output 128x64.
__launch_bounds__(512, 2)
__global__ void gemm2_kernel(const unsigned short* __restrict__ A,
                             const unsigned short* __restrict__ BT,
                             const float* __restrict__ bias,
                             const float* __restrict__ w3,
                             float* __restrict__ scores) {
  extern __shared__ __align__(16) char smem[];

  const int tid  = threadIdx.x;
  const int lane = tid & 63;
  const int wave = tid >> 6;
  const int wm128 = (wave & 1) * 128;
  const int wn64  = (wave >> 1) * 64;
  const int quad = lane >> 4;
  const int r16  = lane & 15;

  const int bx    = blockIdx.x;          // 1024 blocks = 256 mtiles x 4 ntiles
  const int xcd   = bx & 7;
  const int seq   = bx >> 3;
  const int ntile = seq & 3;
  const int mtile = ((seq >> 2) << 3) | xcd;
  const long rowbase = (long)mtile * 256;
  const long colbase = (long)ntile * 256;

  f32x4 acc[8][4];
#pragma unroll
  for (int i = 0; i < 8; i++)
#pragma unroll
    for (int j = 0; j < 4; j++) acc[i][j] = (f32x4){0.f, 0.f, 0.f, 0.f};

  // prologue: stage tile0 {A-lo,A-hi,B-lo,B-hi} + tile1 {A-lo,A-hi,B-lo}
  // (14 loads; no other VMEM loads outstanding — bias/w3 load after loop).
  // vmcnt(6) -> tile0's 8 loads landed; tile1's 3 halves stay in flight.
#pragma unroll
  for (int p = 0; p < 4; p++) stage_half(A, BT, smem, rowbase, colbase, 0, p, tid);
#pragma unroll
  for (int p = 0; p < 3; p++) stage_half(A, BT, smem, rowbase, colbase, 1, p, tid);
  asm volatile("s_waitcnt vmcnt(6)" ::: "memory");
  __builtin_amdgcn_s_barrier();

  // main loop: tiles 0..13 full schedule; vmcnt(6) once per tile.
#pragma unroll 1
  for (int i = 0; i < 7; i++) {
    ktile<2, 6>(smem, A, BT, rowbase, colbase, tid, wm128, wn64, quad, r16,
                2 * i, acc);
    ktile<2, 6>(smem, A, BT, rowbase, colbase, tid, wm128, wn64, quad, r16,
                2 * i + 1, acc);
  }
  // tile 14: stage only (15, B-hi) at PH0, then drain everything.
  ktile<1, 0>(smem, A, BT, rowbase, colbase, tid, wm128, wn64, quad, r16, 14, acc);
  // tile 15: pure compute.
  ktile<0, -1>(smem, A, BT, rowbase, colbase, tid, wm128, wn64, quad, r16, 15, acc);

  // epilogue constants (loaded after the loop so the vmcnt ledger is exact)
  float bias_r[4], w3_r[4];
#pragma unroll
  for (int ni = 0; ni < 4; ni++) {
    int col = (int)colbase + wn64 + ni * 16 + r16;
    bias_r[ni] = bias[col];
    w3_r[ni]   = w3[col];
  }

  // fused epilogue: relu(x + b2) dot w3, shfl-reduce over 16 cols, one
  // atomic per (row, wn) -> 4 atomics per row across the N=1024 extent.
#pragma unroll
  for (int mi = 0; mi < 8; mi++) {
#pragma unroll
    for (int reg = 0; reg < 4; reg++) {
      long row = rowbase + wm128 + mi * 16 + quad * 4 + reg;
      float part = 0.f;
#pragma unroll
      for (int ni = 0; ni < 4; ni++) {
        float v = fmaxf(acc[mi][ni][reg] + bias_r[ni], 0.f);
        part += v * w3_r[ni];
      }
      part += __shfl_xor(part, 1, 16);
      part += __shfl_xor(part, 2, 16);
      part += __shfl_xor(part, 4, 16);
      part += __shfl_xor(part, 8, 16);
      if (r16 == 0) atomicAdd(&scores[row], part);
    }
  }
}

// ---------------------------------------------------------------- GEMM2 fallback (R6)

// Frozen R6 winner (~1012 TF): used only if 128 KiB dynamic LDS is refused.
__launch_bounds__(256, 2)
__global__ void gemm2_128(const unsigned short* __restrict__ A,
                          const unsigned short* __restrict__ BT,
                          const float* __restrict__ bias,
                          const float* __restrict__ w3,
                          float* __restrict__ scores) {
  __shared__ unsigned short As[128 * 64];  // [row][k] 16KB
  __shared__ unsigned short Bs[128 * 64];  // [n][k]   16KB

  const int tid  = threadIdx.x;
  const int lane = tid & 63;
  const int wave = tid >> 6;
  const int wm   = wave & 1;
  const int wn   = wave >> 1;
  const int quad = lane >> 4;
  const int r16  = lane & 15;

  const int bx    = blockIdx.x;
  const int xcd   = bx & 7;
  const int seq   = bx >> 3;
  const int ntile = seq & 7;
  const int mtile = ((seq >> 3) << 3) | xcd;
  const long rowbase = (long)mtile * 128;
  const int  colbase = ntile * 128;

  const f32x4 zero4 = {0.f, 0.f, 0.f, 0.f};
  f32x4 acc[4][4];
#pragma unroll
  for (int i = 0; i < 4; i++)
#pragma unroll
    for (int j = 0; j < 4; j++) acc[i][j] = zero4;

  float bias_r[4], w3_r[4];
#pragma unroll
  for (int ni = 0; ni < 4; ni++) {
    int col = colbase + wn * 64 + ni * 16 + r16;
    bias_r[ni] = bias[col];
    w3_r[ni]   = w3[col];
  }

  int srow[4], skc[4];
#pragma unroll
  for (int i = 0; i < 4; i++) {
    int c = i * 256 + tid;
    srow[i] = c >> 3;
    skc[i]  = (c & 7) ^ (srow[i] & 7);
  }

  for (int k0 = 0; k0 < 1024; k0 += 64) {
#pragma unroll
    for (int i = 0; i < 4; i++) {
      int c = i * 256 + tid;
      async_copy16(A + (rowbase + srow[i]) * 1024 + k0 + skc[i] * 8, &As[c * 8]);
    }
#pragma unroll
    for (int i = 0; i < 4; i++) {
      int c = i * 256 + tid;
      async_copy16(BT + (long)(colbase + srow[i]) * 1024 + k0 + skc[i] * 8, &Bs[c * 8]);
    }
    __syncthreads();

#pragma unroll
    for (int ks = 0; ks < 2; ks++) {
      bf16x8 af[4], bfv[4];
#pragma unroll
      for (int mi = 0; mi < 4; mi++) {
        int r = wm * 64 + mi * 16 + r16;
        int phys = (ks * 4 + quad) ^ (r16 & 7);
        af[mi] = *(const bf16x8*)&As[r * 64 + phys * 8];
      }
#pragma unroll
      for (int ni = 0; ni < 4; ni++) {
        int r = wn * 64 + ni * 16 + r16;
        int phys = (ks * 4 + quad) ^ (r16 & 7);
        bfv[ni] = *(const bf16x8*)&Bs[r * 64 + phys * 8];
      }
#pragma unroll
      for (int mi = 0; mi < 4; mi++)
#pragma unroll
        for (int ni = 0; ni < 4; ni++)
          acc[mi][ni] = __builtin_amdgcn_mfma_f32_16x16x32_bf16(af[mi], bfv[ni],
                                                                acc[mi][ni], 0, 0, 0);
    }
    __syncthreads();
  }

#pragma unroll
  for (int mi = 0; mi < 4; mi++) {
#pragma unroll
    for (int reg = 0; reg < 4; reg++) {
      long row = rowbase + wm * 64 + mi * 16 + quad * 4 + reg;
      float part = 0.f;
#pragma unroll
      for (int ni = 0; ni < 4; ni++) {
        float v = fmaxf(acc[mi][ni][reg] + bias_r[ni], 0.f);
        part += v * w3_r[ni];
      }
      part += __shfl_xor(part, 1, 16);
      part += __shfl_xor(part, 2, 16);
      part += __shfl_xor(part, 4, 16);
      part += __shfl_xor(part, 8, 16);
      if (r16 == 0) atomicAdd(&scores[row], part);
    }
  }
}

// ---------------------------------------------------------------- launch

extern "C" void kernel_launch(void* const* d_in, const int* in_sizes, int n_in,
                              void* d_out, int out_size, void* d_ws, size_t ws_size,
                              hipStream_t stream) {
  const float* pfm  = (const float*)d_in[0];  // (256,19,19)
  const float* cand = (const float*)d_in[1];  // (65536,64)
  const float* W1   = (const float*)d_in[2];  // (832,1024)
  const float* b1   = (const float*)d_in[3];  // (1024,)
  const float* W2   = (const float*)d_in[4];  // (1024,1024)
  const float* b2   = (const float*)d_in[5];  // (1024,)
  const float* W3   = (const float*)d_in[6];  // (1024,1)
  const float* b3   = (const float*)d_in[7];  // (1,)
  float* scores = (float*)d_out;              // (65536,)

  char* ws = (char*)d_ws;
  float*          gp      = (float*)(ws + 0);                // 1 KB
  float*          b1p     = (float*)(ws + 1024);             // 4 KB
  unsigned short* Tb      = (unsigned short*)(ws + 8192);    // 1,478,656
  int*            go_off  = (int*)(ws + 1486848);            // 256 KB
  int*            to_off  = (int*)(ws + 1748992);            // 256 KB
  unsigned short* w1cT    = (unsigned short*)(ws + 2011136); // 128 KB
  unsigned short* w2T     = (unsigned short*)(ws + 2142208); // 2 MB
  unsigned short* h1      = (unsigned short*)(ws + 4239360); // 128 MB
  // total ws need: 138,457,088 bytes
  if (ws_size < 138457088) return;  // loud correctness failure instead of corruption

  // one-time: opt in to 128 KiB dynamic LDS for the 8-phase gemm2.
  static int use256 = -1;
  if (use256 < 0) {
    use256 = (hipFuncSetAttribute((const void*)gemm2_kernel,
                                  hipFuncAttributeMaxDynamicSharedMemorySize,
                                  131072) == hipSuccess) ? 1 : 0;
  }

  pool_kernel<<<64, 256, 0, stream>>>(pfm, gp, b1, b1p);
  prep_kernel<<<1520, 256, 0, stream>>>(pfm, cand, W1, gp, W2, b3,
                                        go_off, to_off, scores, w1cT, w2T, Tb, b1p);
  // h1 = relu(cand@W1c + T_go[g] + T_to[t] + b1')   M=65536,K=64
  gemm1_kernel<<<4096, 256, 0, stream>>>(cand, w1cT, h1, Tb, go_off, to_off, b1p);
  // scores += relu(h1@W2 + b2) @ w3                 M=65536,K=1024
  if (use256) {
    gemm2_kernel<<<1024, 512, 131072, stream>>>(h1, w2T, b2, W3, scores);
  } else {
    gemm2_128<<<4096, 256, 0, stream>>>(h1, w2T, b2, W3, scores);
  }
}

// Round 4
// 272.588 us; speedup vs baseline: 1.3153x; 1.0516x over previous
//
#include <hip/hip_runtime.h>

// CandidateScorer on MI355X (gfx950).
//
// Math (exact rewrite of the reference):
//   gp-part of combined is candidate-independent      -> folded into bias b1'
//   go/to gathers take only 361 distinct values each  -> precomputed tables
//   h1[n,j] = relu(T_go[go[n],j] + T_to[to[n],j] + (cand @ W1c)[n,j] + b1'[j])
//   scores  = relu(h1 @ W2 + b2) @ W3 + b3   (GEMM3 fused into GEMM2 epilogue)
//
// R1..R6: 128^2 2-phase gemm2 at ~1012 TF (frozen as gemm2_128 fallback).
// R12: 8-phase 256^2 FAILED (WAR race). R13: race-free but spilled hard
//   (frag peak 96 -> WRITE 76 MB, 227 us). R14: frag peak 80 -> WRITE
//   36.8 MB (still ~20 MB spill), MfmaUtil 38.4%, 152 us.
// R15 (this round): frag peak 64. Reads: PH0 A0+B01, PH1 B23, PH2 A1.
//   af0 dies as af1 is born; bf01 dies as bf23 replaces it. Completion:
//   B free after PH1, A free after PH2. Stage: PH0:(t+1,A-hi)->other buf;
//   PH2:(t+2,B-lo); PH3:(t+2,B-hi)+(t+2,A-lo). vmcnt(6)/tile = t+2's 3
//   parts in flight, t+1 proven landed. Arch-VGPR budget (128, CSV shows
//   arch side only; acc=128 AGPR on unified file): 64 frags + ~40 addr.

using bf16x8 = __attribute__((ext_vector_type(8))) __bf16;
using f32x4  = __attribute__((ext_vector_type(4))) float;
using i32x4  = __attribute__((ext_vector_type(4))) int;

__device__ __forceinline__ unsigned short f2bf(float f) {
  unsigned int u = __float_as_uint(f);
  u += 0x7fffu + ((u >> 16) & 1u);          // round-to-nearest-even
  return (unsigned short)(u >> 16);
}
__device__ __forceinline__ float bf2f(unsigned int s) {
  return __uint_as_float(s << 16);
}

// Async global->LDS, 16B per lane. LDS dest is wave-uniform base + lane*16.
__device__ __forceinline__ void async_copy16(const void* g, void* l) {
  __builtin_amdgcn_global_load_lds(
      (__attribute__((address_space(1))) void*)(unsigned long long)g,
      (__attribute__((address_space(3))) void*)(unsigned int)(unsigned long long)l,
      16, 0, 0);
}

// ---------------------------------------------------------------- pool
// 64 blocks x 256 threads: wave w reduces channel bx*4+w (fully parallel).
// Blocks 0-3 additionally init b1p = b1 (atomic target for prep's b1p range).
__global__ void pool_kernel(const float* __restrict__ pfm, float* __restrict__ gp,
                            const float* __restrict__ b1, float* __restrict__ b1p) {
  int t = threadIdx.x, bx = blockIdx.x;
  int wave = t >> 6, lane = t & 63;
  int c = bx * 4 + wave;
  float s = 0.f;
  for (int i = lane; i < 361; i += 64) s += pfm[c * 361 + i];
#pragma unroll
  for (int off = 32; off > 0; off >>= 1) s += __shfl_down(s, off, 64);
  if (lane == 0) gp[c] = s * (1.0f / 361.0f);
  if (bx < 4) b1p[bx * 256 + t] = b1[bx * 256 + t];
}

// ---------------------------------------------------------------- fused prep
// Block ranges (long pole first):
//   [0,368)      Ttab (bf16): T[s][pos][j] = sum_c pfm[c][pos]*W1[s*256+c][j]
//   [368,496)    b1p[j] += sum over 8 channels of gp[c]*W1[512+c][j] (atomic)
//   [496,752)    w2T[n][k] = bf16(W2[k][n])  (64x64 LDS-tiled transpose)
//   [752,1008)   go/to decode
//   [1008,1264)  scores = b3
//   [1264,1520)  w1cT[n][k] = bf16(W1[768+k][n])
__global__ void prep_kernel(const float* __restrict__ pfm, const float* __restrict__ cand,
                            const float* __restrict__ W1, const float* __restrict__ gp,
                            const float* __restrict__ W2, const float* __restrict__ b3,
                            int* __restrict__ go_off, int* __restrict__ to_off,
                            float* __restrict__ scores,
                            unsigned short* __restrict__ w1cT,
                            unsigned short* __restrict__ w2T,
                            unsigned short* __restrict__ Tb,
                            float* __restrict__ b1p) {
  __shared__ __align__(16) char smem[16640];
  int bx = blockIdx.x, t = threadIdx.x;

  if (bx < 368) {
    int b = bx;                      // 2 * 46 * 4 = 368 blocks
    int s = b / 184;
    int rem = b % 184;
    int p8 = rem >> 2;
    int jc = rem & 3;
    int j = jc * 256 + t;
    float (*pf)[256] = (float(*)[256])smem;   // [8][256] = 8KB
#pragma unroll
    for (int i = 0; i < 8; i++) {
      int p = p8 * 8 + i;
      pf[i][t] = (p < 361) ? pfm[t * 361 + p] : 0.f;   // t = channel
    }
    __syncthreads();
    float acc[8] = {0.f, 0.f, 0.f, 0.f, 0.f, 0.f, 0.f, 0.f};
    for (int c = 0; c < 256; c++) {
      float w = W1[(size_t)(s * 256 + c) * 1024 + j];
#pragma unroll
      for (int i = 0; i < 8; i++) acc[i] += pf[i][c] * w;
    }
#pragma unroll
    for (int i = 0; i < 8; i++) {
      int p = p8 * 8 + i;
      if (p < 361) Tb[((size_t)s * 361 + p) * 1024 + j] = f2bf(acc[i]);
    }
  } else if (bx < 496) {
    int b = bx - 368;                // 128 blocks: (jc 0..3) x (cchunk 0..31)
    int j = (b & 3) * 256 + t;
    int c0 = (b >> 2) * 8;
    float acc = 0.f;
#pragma unroll
    for (int i = 0; i < 8; i++)
      acc += gp[c0 + i] * W1[(size_t)(512 + c0 + i) * 1024 + j];
    atomicAdd(&b1p[j], acc);
  } else if (bx < 752) {
    int b = bx - 496;                // 256 tiles (16 x 16)
    float (*Ts)[65] = (float(*)[65])smem;     // [64][65] = 16640 B
    int kt = b >> 4, nt = b & 15;
#pragma unroll
    for (int i = 0; i < 4; i++) {
      int c = i * 256 + t;           // 1024 f32x4 chunks
      int r = c >> 4, ch = c & 15;
      f32x4 v = *(const f32x4*)&W2[(size_t)(kt * 64 + r) * 1024 + nt * 64 + ch * 4];
      Ts[r][ch * 4 + 0] = v[0]; Ts[r][ch * 4 + 1] = v[1];
      Ts[r][ch * 4 + 2] = v[2]; Ts[r][ch * 4 + 3] = v[3];
    }
    __syncthreads();
#pragma unroll
    for (int i = 0; i < 2; i++) {
      int c = i * 256 + t;           // 512 out-chunks of 8 bf16
      int n = c >> 3, ch = c & 7;
      unsigned short pack[8];
#pragma unroll
      for (int j = 0; j < 8; j++) pack[j] = f2bf(Ts[ch * 8 + j][n]);
      *(i32x4*)&w2T[(size_t)(nt * 64 + n) * 1024 + kt * 64 + ch * 8] = *(i32x4*)pack;
    }
  } else if (bx < 1008) {
    int n = (bx - 752) * 256 + t;
    const float* cf = cand + (size_t)n * 64;
    int gr = min(max((int)(cf[5] * 18.0f), 0), 18);
    int gc = min(max((int)(cf[6] * 18.0f), 0), 18);
    int tr = min(max((int)(cf[7] * 18.0f), 0), 18);
    int tc = min(max((int)(cf[8] * 18.0f), 0), 18);
    go_off[n] = gr * 19 + gc;
    to_off[n] = tr * 19 + tc;
  } else if (bx < 1264) {
    scores[(bx - 1008) * 256 + t] = b3[0];
  } else {
    int o = (bx - 1264) * 256 + t;   // < 65536
    int n = o >> 6, k = o & 63;
    w1cT[o] = f2bf(W1[(size_t)(768 + k) * 1024 + n]);
  }
}

// ---------------------------------------------------------------- GEMM1 (fused)

// h1(65536 x 1024) = relu(cand(f32) @ W1c + T_go[go] + T_to[to] + b1p)
// 128x128 tile, K=64 single step. A staged via f32 load + convert + ds_write;
// B via async_copy16. LDS XOR-swizzled (chunk (row,s) holds kchunk s^(row&7)).
__launch_bounds__(256, 2)
__global__ void gemm1_kernel(const float* __restrict__ cand,
                             const unsigned short* __restrict__ w1cT,
                             unsigned short* __restrict__ h1out,
                             const unsigned short* __restrict__ Tb,
                             const int* __restrict__ go_off,
                             const int* __restrict__ to_off,
                             const float* __restrict__ bias) {
  __shared__ __align__(16) char smem[34816];           // max(32K stage, 34K Cs)
  unsigned short* As = (unsigned short*)smem;          // [128][64] 16KB
  unsigned short* Bs = (unsigned short*)(smem + 16384);// [128][64] 16KB
  unsigned short* Cs = (unsigned short*)smem;          // [128][136] bf16 (aliased)

  const int tid  = threadIdx.x;
  const int lane = tid & 63;
  const int wave = tid >> 6;
  const int wm   = wave & 1;
  const int wn   = wave >> 1;
  const int quad = lane >> 4;
  const int r16  = lane & 15;

  const int bx    = blockIdx.x;
  const int xcd   = bx & 7;
  const int seq   = bx >> 3;
  const int ntile = seq & 7;
  const int mtile = ((seq >> 3) << 3) | xcd;
  const long rowbase = (long)mtile * 128;
  const int  colbase = ntile * 128;

  // ---- stage A: load f32, convert, ds_write (4 chunks of 16B per thread)
#pragma unroll
  for (int i = 0; i < 4; i++) {
    int c = i * 256 + tid;                 // physical chunk
    int row = c >> 3, s = c & 7;
    int kc = s ^ (row & 7);                // logical k-chunk
    const float* src = cand + (rowbase + row) * 64 + kc * 8;
    f32x4 v0 = *(const f32x4*)src;
    f32x4 v1 = *(const f32x4*)(src + 4);
    unsigned int p[4];
    p[0] = f2bf(v0[0]) | ((unsigned int)f2bf(v0[1]) << 16);
    p[1] = f2bf(v0[2]) | ((unsigned int)f2bf(v0[3]) << 16);
    p[2] = f2bf(v1[0]) | ((unsigned int)f2bf(v1[1]) << 16);
    p[3] = f2bf(v1[2]) | ((unsigned int)f2bf(v1[3]) << 16);
    *(i32x4*)&As[c * 8] = *(i32x4*)p;
  }
  // ---- stage B: async copy w1cT tile (4 chunks per thread)
#pragma unroll
  for (int i = 0; i < 4; i++) {
    int c = i * 256 + tid;
    int row = c >> 3, s = c & 7;
    int kc = s ^ (row & 7);
    async_copy16(w1cT + (colbase + row) * 64 + kc * 8, &Bs[c * 8]);
  }
  __syncthreads();

  const f32x4 zero4 = {0.f, 0.f, 0.f, 0.f};
  f32x4 acc[4][4];
#pragma unroll
  for (int i = 0; i < 4; i++)
#pragma unroll
    for (int j = 0; j < 4; j++) acc[i][j] = zero4;

#pragma unroll
  for (int ks = 0; ks < 2; ks++) {
    bf16x8 af[4], bfv[4];
#pragma unroll
    for (int mi = 0; mi < 4; mi++) {
      int r = wm * 64 + mi * 16 + r16;
      int phys = (ks * 4 + quad) ^ (r16 & 7);
      af[mi] = *(const bf16x8*)&As[r * 64 + phys * 8];
    }
#pragma unroll
    for (int ni = 0; ni < 4; ni++) {
      int r = wn * 64 + ni * 16 + r16;
      int phys = (ks * 4 + quad) ^ (r16 & 7);
      bfv[ni] = *(const bf16x8*)&Bs[r * 64 + phys * 8];
    }
#pragma unroll
    for (int mi = 0; mi < 4; mi++)
#pragma unroll
      for (int ni = 0; ni < 4; ni++)
        acc[mi][ni] = __builtin_amdgcn_mfma_f32_16x16x32_bf16(af[mi], bfv[ni],
                                                              acc[mi][ni], 0, 0, 0);
  }
  __syncthreads();   // staging LDS dead; Cs takes over

  // Phase 1: Cs[r][c] = bf16(T_go[go[r]][c] + T_to[to[r]][c] + bias[c]).
#pragma unroll
  for (int i = 0; i < 8; i++) {
    int c = i * 256 + tid;                    // 2048 chunks of 8 cols
    int r = c >> 4, ch = c & 15;
    long grow = rowbase + r;
    const unsigned short* tg = Tb + (long)go_off[grow] * 1024 + colbase + ch * 8;
    const unsigned short* tt = Tb + 361L * 1024 + (long)to_off[grow] * 1024 + colbase + ch * 8;
    i32x4 ga = *(const i32x4*)tg;
    i32x4 gb = *(const i32x4*)tt;
    const float* bp = bias + colbase + ch * 8;
    f32x4 b0 = *(const f32x4*)bp;
    f32x4 b1v = *(const f32x4*)(bp + 4);
    unsigned int p[4];
#pragma unroll
    for (int w = 0; w < 4; w++) {
      unsigned int ua = (unsigned int)ga[w], ub = (unsigned int)gb[w];
      float lo = bf2f(ua & 0xffffu) + bf2f(ub & 0xffffu);
      float hi = bf2f(ua >> 16)     + bf2f(ub >> 16);
      lo += (w < 2) ? b0[w * 2]     : b1v[(w - 2) * 2];
      hi += (w < 2) ? b0[w * 2 + 1] : b1v[(w - 2) * 2 + 1];
      p[w] = f2bf(lo) | ((unsigned int)f2bf(hi) << 16);
    }
    *(i32x4*)&Cs[r * 136 + ch * 8] = *(i32x4*)p;
  }
  __syncthreads();
  // Phase 2: in-place RMW — each (rloc,cloc) touched by exactly one thread.
  // C/D layout: col = lane&15, row = quad*4 + reg  (m89/m91-verified)
#pragma unroll
  for (int mi = 0; mi < 4; mi++) {
#pragma unroll
    for (int reg = 0; reg < 4; reg++) {
      int rloc = wm * 64 + mi * 16 + quad * 4 + reg;
#pragma unroll
      for (int ni = 0; ni < 4; ni++) {
        int cloc = wn * 64 + ni * 16 + r16;
        float v = acc[mi][ni][reg] + bf2f(Cs[rloc * 136 + cloc]);
        Cs[rloc * 136 + cloc] = f2bf(fmaxf(v, 0.f));
      }
    }
  }
  __syncthreads();
  // Phase 3: 16B-coalesced global stores.
#pragma unroll
  for (int i = 0; i < 8; i++) {
    int c = i * 256 + tid;
    int r = c >> 4, cc = c & 15;
    *(i32x4*)(h1out + (rowbase + r) * 1024 + colbase + cc * 8) =
        *(const i32x4*)&Cs[r * 136 + cc * 8];
  }
}

// ---------------------------------------------------------------- GEMM2 (8-phase 256^2)

// LDS map (byte offsets into 128 KiB dynamic smem), per buffer b = t&1:
//   A(b) = b*65536          : 2 halves x [128 rows][8 slots of 16B]   (32 KB)
//   B(b) = b*65536 + 32768  : same                                    (32 KB)
// part p: 0=A-lo 1=A-hi 2=B-lo 3=B-hi. One call = 2 loads/thread = 16 KB.
// Chunk c = row*8 + s holds logical k-chunk s^(row&7) (XOR swizzle via
// pre-swizzled global source; read side applies the same involution).
__device__ __forceinline__ void stage_half(const unsigned short* __restrict__ A,
                                           const unsigned short* __restrict__ BT,
                                           char* smem, long rowbase, long colbase,
                                           int t, int p, int tid) {
  const unsigned short* src = (p < 2) ? A : BT;
  const long rbase = ((p < 2) ? rowbase : colbase) + (long)((p & 1) * 128);
  char* dst = smem + (t & 1) * 65536 + (p >> 1) * 32768 + (p & 1) * 16384;
  const long k0 = (long)t * 64;
#pragma unroll
  for (int j = 0; j < 2; j++) {
    const int c = j * 512 + tid;
    const int lrow = c >> 3;
    const int kc = (c & 7) ^ (lrow & 7);
    async_copy16(src + (rbase + lrow) * 1024 + k0 + kc * 8, dst + c * 16);
  }
}

// Fragment read: tile-row r in [0,256), logical k-chunk kq in [0,8).
__device__ __forceinline__ bf16x8 lds_frag(const char* base, int r, int kq) {
  const int lrow = r & 127;
  return *(const bf16x8*)(base + (r >> 7) * 16384 + lrow * 128 +
                          ((kq ^ (lrow & 7)) * 16));
}

// One K-tile (BK=64), 4 phases, frag-peak-64 schedule:
//   PH0: read A0(8)+B01(4); stage (t+1,A-hi)->other buf; MFMA (mh0,n01)
//   PH1: read B23(4);                                    MFMA (mh0,n23)
//   PH2: read A1(8);        stage (t+2,B-lo);            MFMA (mh1,n01)
//   PH3: no reads;          stage (t+2,B-hi)+(t+2,A-lo); MFMA (mh1,n23)
// Liveness: af0 dies after PH1 as af1 is born in PH2; bf01 dies after PH2
// as bf23 was born in PH1 -> peak 64 frag VGPRs at every phase.
// Read-completion (published via per-wave lgkmcnt before each bar#2):
//   B-lo/B-hi fully read after PH1; A-lo/A-hi after PH2 -> every stage
//   targets a freed region. (t+1,A-hi) goes to the other buffer, whose
//   tenant (t-1) completed a full tile ago.
// Ledger: 8 issues/tile (PH0:2, PH2:2, PH3:4). VMODE 6 = vmcnt(6) at tile
// end keeps exactly t+2's B-lo/B-hi/A-lo in flight, proving t+1 landed.
// NSTAGE: 2 = full, 1 = PH0 only, 0 = none.
template <int NSTAGE, int VMODE>
__device__ __forceinline__ void ktile(char* smem,
                                      const unsigned short* __restrict__ A,
                                      const unsigned short* __restrict__ BT,
                                      long rowbase, long colbase, int tid,
                                      int wm128, int wn64, int quad, int r16,
                                      int t, f32x4 (&acc)[8][4]) {
  const char* a_base = smem + (t & 1) * 65536;
  const char* b_base = a_base + 32768;
  bf16x8 af0[4][2], af1[4][2], bf01[2][2], bf23[2][2];

  // ---- PH0: read A0 + B01; stage (t+1, A-hi); MFMA (mh0, n01)
#pragma unroll
  for (int mi = 0; mi < 4; mi++)
#pragma unroll
    for (int ks = 0; ks < 2; ks++)
      af0[mi][ks] = lds_frag(a_base, wm128 + mi * 16 + r16, ks * 4 + quad);
#pragma unroll
  for (int ni = 0; ni < 2; ni++)
#pragma unroll
    for (int ks = 0; ks < 2; ks++)
      bf01[ni][ks] = lds_frag(b_base, wn64 + ni * 16 + r16, ks * 4 + quad);
  if (NSTAGE >= 1) stage_half(A, BT, smem, rowbase, colbase, t + 1, 1, tid);
  __builtin_amdgcn_s_barrier();
  asm volatile("s_waitcnt lgkmcnt(0)" ::: "memory");
  __builtin_amdgcn_s_setprio(1);
#pragma unroll
  for (int mi = 0; mi < 4; mi++)
#pragma unroll
    for (int ni = 0; ni < 2; ni++)
#pragma unroll
      for (int ks = 0; ks < 2; ks++)
        acc[mi][ni] = __builtin_amdgcn_mfma_f32_16x16x32_bf16(af0[mi][ks], bf01[ni][ks],
                                                              acc[mi][ni], 0, 0, 0);
  __builtin_amdgcn_s_setprio(0);
  __builtin_amdgcn_s_barrier();

  // ---- PH1: read B23; MFMA (mh0, n23)
#pragma unroll
  for (int ni = 0; ni < 2; ni++)
#pragma unroll
    for (int ks = 0; ks < 2; ks++)
      bf23[ni][ks] = lds_frag(b_base, wn64 + (2 + ni) * 16 + r16, ks * 4 + quad);
  __builtin_amdgcn_s_barrier();
  asm volatile("s_waitcnt lgkmcnt(0)" ::: "memory");
  __builtin_amdgcn_s_setprio(1);
#pragma unroll
  for (int mi = 0; mi < 4; mi++)
#pragma unroll
    for (int ni = 0; ni < 2; ni++)
#pragma unroll
      for (int ks = 0; ks < 2; ks++)
        acc[mi][2 + ni] = __builtin_amdgcn_mfma_f32_16x16x32_bf16(af0[mi][ks], bf23[ni][ks],
                                                                  acc[mi][2 + ni], 0, 0, 0);
  __builtin_amdgcn_s_setprio(0);
  __builtin_amdgcn_s_barrier();

  // ---- PH2: read A1; stage (t+2, B-lo); MFMA (mh1, n01)
#pragma unroll
  for (int mi = 0; mi < 4; mi++)
#pragma unroll
    for (int ks = 0; ks < 2; ks++)
      af1[mi][ks] = lds_frag(a_base, wm128 + 64 + mi * 16 + r16, ks * 4 + quad);
  if (NSTAGE >= 2) stage_half(A, BT, smem, rowbase, colbase, t + 2, 2, tid);
  __builtin_amdgcn_s_barrier();
  asm volatile("s_waitcnt lgkmcnt(0)" ::: "memory");
  __builtin_amdgcn_s_setprio(1);
#pragma unroll
  for (int mi = 0; mi < 4; mi++)
#pragma unroll
    for (int ni = 0; ni < 2; ni++)
#pragma unroll
      for (int ks = 0; ks < 2; ks++)
        acc[4 + mi][ni] = __builtin_amdgcn_mfma_f32_16x16x32_bf16(af1[mi][ks], bf01[ni][ks],
                                                                  acc[4 + mi][ni], 0, 0, 0);
  __builtin_amdgcn_s_setprio(0);
  __builtin_amdgcn_s_barrier();

  // ---- PH3: stage (t+2, B-hi) + (t+2, A-lo); MFMA (mh1, n23); vmcnt; bar
  if (NSTAGE >= 2) {
    stage_half(A, BT, smem, rowbase, colbase, t + 2, 3, tid);
    stage_half(A, BT, smem, rowbase, colbase, t + 2, 0, tid);
  }
  __builtin_amdgcn_s_barrier();
  __builtin_amdgcn_s_setprio(1);
#pragma unroll
  for (int mi = 0; mi < 4; mi++)
#pragma unroll
    for (int ni = 0; ni < 2; ni++)
#pragma unroll
      for (int ks = 0; ks < 2; ks++)
        acc[4 + mi][2 + ni] = __builtin_amdgcn_mfma_f32_16x16x32_bf16(af1[mi][ks], bf23[ni][ks],
                                                                      acc[4 + mi][2 + ni], 0, 0, 0);
  __builtin_amdgcn_s_setprio(0);
  if (VMODE == 6)      asm volatile("s_waitcnt vmcnt(6)" ::: "memory");
  else if (VMODE == 0) asm volatile("s_waitcnt vmcnt(0)" ::: "memory");
  __builtin_amdgcn_s_barrier();
}

// scores += relu(h1(65536x1024,bf16) @ W2 + b2) @ W3.
// 256x256 tile, BK=64, 8 waves (2Mx4N), per-wave output 128x64.
__launch_bounds__(512, 2)
__global__ void gemm2_kernel(const unsigned short* __restrict__ A,
                             const unsigned short* __restrict__ BT,
                             const float* __restrict__ bias,
                             const float* __restrict__ w3,
                             float* __restrict__ scores) {
  extern __shared__ __align__(16) char smem[];

  const int tid  = threadIdx.x;
  const int lane = tid & 63;
  const int wave = tid >> 6;
  const int wm128 = (wave & 1) * 128;
  const int wn64  = (wave >> 1) * 64;
  const int quad = lane >> 4;
  const int r16  = lane & 15;

  const int bx    = blockIdx.x;          // 1024 blocks = 256 mtiles x 4 ntiles
  const int xcd   = bx & 7;
  const int seq   = bx >> 3;
  const int ntile = seq & 3;
  const int mtile = ((seq >> 2) << 3) | xcd;
  const long rowbase = (long)mtile * 256;
  const long colbase = (long)ntile * 256;

  f32x4 acc[8][4];
#pragma unroll
  for (int i = 0; i < 8; i++)
#pragma unroll
    for (int j = 0; j < 4; j++) acc[i][j] = (f32x4){0.f, 0.f, 0.f, 0.f};

  // prologue: stage tile0 {all 4 parts} + tile1 {B-lo, B-hi, A-lo}
  // (14 loads; no other VMEM loads outstanding — bias/w3 load after loop).
  // vmcnt(6) -> tile0's 8 loads landed; tile1's 3 parts stay in flight.
  // Tile0 PH0 then stages (1, A-hi), completing tile1.
#pragma unroll
  for (int p = 0; p < 4; p++) stage_half(A, BT, smem, rowbase, colbase, 0, p, tid);
  stage_half(A, BT, smem, rowbase, colbase, 1, 2, tid);
  stage_half(A, BT, smem, rowbase, colbase, 1, 3, tid);
  stage_half(A, BT, smem, rowbase, colbase, 1, 0, tid);
  asm volatile("s_waitcnt vmcnt(6)" ::: "memory");
  __builtin_amdgcn_s_barrier();

  // main loop: tiles 0..13 full schedule; vmcnt(6) once per tile.
#pragma unroll 1
  for (int i = 0; i < 7; i++) {
    ktile<2, 6>(smem, A, BT, rowbase, colbase, tid, wm128, wn64, quad, r16,
                2 * i, acc);
    ktile<2, 6>(smem, A, BT, rowbase, colbase, tid, wm128, wn64, quad, r16,
                2 * i + 1, acc);
  }
  // tile 14: stage only (15, A-hi) at PH0, then drain everything.
  ktile<1, 0>(smem, A, BT, rowbase, colbase, tid, wm128, wn64, quad, r16, 14, acc);
  // tile 15: pure compute.
  ktile<0, -1>(smem, A, BT, rowbase, colbase, tid, wm128, wn64, quad, r16, 15, acc);

  // epilogue constants (loaded after the loop so the vmcnt ledger is exact)
  float bias_r[4], w3_r[4];
#pragma unroll
  for (int ni = 0; ni < 4; ni++) {
    int col = (int)colbase + wn64 + ni * 16 + r16;
    bias_r[ni] = bias[col];
    w3_r[ni]   = w3[col];
  }

  // fused epilogue: relu(x + b2) dot w3, shfl-reduce over 16 cols, one
  // atomic per (row, wn) -> 4 atomics per row across the N=1024 extent.
#pragma unroll
  for (int mi = 0; mi < 8; mi++) {
#pragma unroll
    for (int reg = 0; reg < 4; reg++) {
      long row = rowbase + wm128 + mi * 16 + quad * 4 + reg;
      float part = 0.f;
#pragma unroll
      for (int ni = 0; ni < 4; ni++) {
        float v = fmaxf(acc[mi][ni][reg] + bias_r[ni], 0.f);
        part += v * w3_r[ni];
      }
      part += __shfl_xor(part, 1, 16);
      part += __shfl_xor(part, 2, 16);
      part += __shfl_xor(part, 4, 16);
      part += __shfl_xor(part, 8, 16);
      if (r16 == 0) atomicAdd(&scores[row], part);
    }
  }
}

// ---------------------------------------------------------------- GEMM2 fallback (R6)

// Frozen R6 winner (~1012 TF): used only if 128 KiB dynamic LDS is refused.
__launch_bounds__(256, 2)
__global__ void gemm2_128(const unsigned short* __restrict__ A,
                          const unsigned short* __restrict__ BT,
                          const float* __restrict__ bias,
                          const float* __restrict__ w3,
                          float* __restrict__ scores) {
  __shared__ unsigned short As[128 * 64];  // [row][k] 16KB
  __shared__ unsigned short Bs[128 * 64];  // [n][k]   16KB

  const int tid  = threadIdx.x;
  const int lane = tid & 63;
  const int wave = tid >> 6;
  const int wm   = wave & 1;
  const int wn   = wave >> 1;
  const int quad = lane >> 4;
  const int r16  = lane & 15;

  const int bx    = blockIdx.x;
  const int xcd   = bx & 7;
  const int seq   = bx >> 3;
  const int ntile = seq & 7;
  const int mtile = ((seq >> 3) << 3) | xcd;
  const long rowbase = (long)mtile * 128;
  const int  colbase = ntile * 128;

  const f32x4 zero4 = {0.f, 0.f, 0.f, 0.f};
  f32x4 acc[4][4];
#pragma unroll
  for (int i = 0; i < 4; i++)
#pragma unroll
    for (int j = 0; j < 4; j++) acc[i][j] = zero4;

  float bias_r[4], w3_r[4];
#pragma unroll
  for (int ni = 0; ni < 4; ni++) {
    int col = colbase + wn * 64 + ni * 16 + r16;
    bias_r[ni] = bias[col];
    w3_r[ni]   = w3[col];
  }

  int srow[4], skc[4];
#pragma unroll
  for (int i = 0; i < 4; i++) {
    int c = i * 256 + tid;
    srow[i] = c >> 3;
    skc[i]  = (c & 7) ^ (srow[i] & 7);
  }

  for (int k0 = 0; k0 < 1024; k0 += 64) {
#pragma unroll
    for (int i = 0; i < 4; i++) {
      int c = i * 256 + tid;
      async_copy16(A + (rowbase + srow[i]) * 1024 + k0 + skc[i] * 8, &As[c * 8]);
    }
#pragma unroll
    for (int i = 0; i < 4; i++) {
      int c = i * 256 + tid;
      async_copy16(BT + (long)(colbase + srow[i]) * 1024 + k0 + skc[i] * 8, &Bs[c * 8]);
    }
    __syncthreads();

#pragma unroll
    for (int ks = 0; ks < 2; ks++) {
      bf16x8 af[4], bfv[4];
#pragma unroll
      for (int mi = 0; mi < 4; mi++) {
        int r = wm * 64 + mi * 16 + r16;
        int phys = (ks * 4 + quad) ^ (r16 & 7);
        af[mi] = *(const bf16x8*)&As[r * 64 + phys * 8];
      }
#pragma unroll
      for (int ni = 0; ni < 4; ni++) {
        int r = wn * 64 + ni * 16 + r16;
        int phys = (ks * 4 + quad) ^ (r16 & 7);
        bfv[ni] = *(const bf16x8*)&Bs[r * 64 + phys * 8];
      }
#pragma unroll
      for (int mi = 0; mi < 4; mi++)
#pragma unroll
        for (int ni = 0; ni < 4; ni++)
          acc[mi][ni] = __builtin_amdgcn_mfma_f32_16x16x32_bf16(af[mi], bfv[ni],
                                                                acc[mi][ni], 0, 0, 0);
    }
    __syncthreads();
  }

#pragma unroll
  for (int mi = 0; mi < 4; mi++) {
#pragma unroll
    for (int reg = 0; reg < 4; reg++) {
      long row = rowbase + wm * 64 + mi * 16 + quad * 4 + reg;
      float part = 0.f;
#pragma unroll
      for (int ni = 0; ni < 4; ni++) {
        float v = fmaxf(acc[mi][ni][reg] + bias_r[ni], 0.f);
        part += v * w3_r[ni];
      }
      part += __shfl_xor(part, 1, 16);
      part += __shfl_xor(part, 2, 16);
      part += __shfl_xor(part, 4, 16);
      part += __shfl_xor(part, 8, 16);
      if (r16 == 0) atomicAdd(&scores[row], part);
    }
  }
}

// ---------------------------------------------------------------- launch

extern "C" void kernel_launch(void* const* d_in, const int* in_sizes, int n_in,
                              void* d_out, int out_size, void* d_ws, size_t ws_size,
                              hipStream_t stream) {
  const float* pfm  = (const float*)d_in[0];  // (256,19,19)
  const float* cand = (const float*)d_in[1];  // (65536,64)
  const float* W1   = (const float*)d_in[2];  // (832,1024)
  const float* b1   = (const float*)d_in[3];  // (1024,)
  const float* W2   = (const float*)d_in[4];  // (1024,1024)
  const float* b2   = (const float*)d_in[5];  // (1024,)
  const float* W3   = (const float*)d_in[6];  // (1024,1)
  const float* b3   = (const float*)d_in[7];  // (1,)
  float* scores = (float*)d_out;              // (65536,)

  char* ws = (char*)d_ws;
  float*          gp      = (float*)(ws + 0);                // 1 KB
  float*          b1p     = (float*)(ws + 1024);             // 4 KB
  unsigned short* Tb      = (unsigned short*)(ws + 8192);    // 1,478,656
  int*            go_off  = (int*)(ws + 1486848);            // 256 KB
  int*            to_off  = (int*)(ws + 1748992);            // 256 KB
  unsigned short* w1cT    = (unsigned short*)(ws + 2011136); // 128 KB
  unsigned short* w2T     = (unsigned short*)(ws + 2142208); // 2 MB
  unsigned short* h1      = (unsigned short*)(ws + 4239360); // 128 MB
  // total ws need: 138,457,088 bytes
  if (ws_size < 138457088) return;  // loud correctness failure instead of corruption

  // one-time: opt in to 128 KiB dynamic LDS for the 8-phase gemm2.
  static int use256 = -1;
  if (use256 < 0) {
    use256 = (hipFuncSetAttribute((const void*)gemm2_kernel,
                                  hipFuncAttributeMaxDynamicSharedMemorySize,
                                  131072) == hipSuccess) ? 1 : 0;
  }

  pool_kernel<<<64, 256, 0, stream>>>(pfm, gp, b1, b1p);
  prep_kernel<<<1520, 256, 0, stream>>>(pfm, cand, W1, gp, W2, b3,
                                        go_off, to_off, scores, w1cT, w2T, Tb, b1p);
  // h1 = relu(cand@W1c + T_go[g] + T_to[t] + b1')   M=65536,K=64
  gemm1_kernel<<<4096, 256, 0, stream>>>(cand, w1cT, h1, Tb, go_off, to_off, b1p);
  // scores += relu(h1@W2 + b2) @ w3                 M=65536,K=1024
  if (use256) {
    gemm2_kernel<<<1024, 512, 131072, stream>>>(h1, w2T, b2, W3, scores);
  } else {
    gemm2_128<<<4096, 256, 0, stream>>>(h1, w2T, b2, W3, scores);
  }
}